// Round 6
// baseline (292.680 us; speedup 1.0000x reference)
//
#include <hip/hip_runtime.h>

// Problem constants
#define N_TOTAL   65536   // B*H*W = 64*32*32
#define HW_SZ     1024    // H*W
#define CDIM      64      // embedding dim (= C)
#define K_CODES   1024
#define OUT_ELEMS 4194304 // 64*64*32*32
#define QT        64      // queries per argmin block
#define CHUNK     128     // codes staged per LDS chunk
#define NCHUNK    (K_CODES / CHUNK)
#define TAU       0.02f   // rescue margin (>=30x the ~6e-4 worst-case bf16x3 error)
#define RESCUE_BLOCKS 2048

// ws layout (bytes):
//   0      : enorm[1024]  float
//   4096   : hist[1024]   uint
//   8192   : counter      uint
//   12288  : e_hi[1024*64] bf16-as-short
//   143360 : e_lo[1024*64] bf16-as-short
//   274432 : idx[65536]   int
//   536576 : list[65536]  ushort (flagged queries)
//   664576 : partials[1024] float

typedef __attribute__((ext_vector_type(8))) short short8;
typedef __attribute__((ext_vector_type(4))) float f32x4;

__device__ __forceinline__ unsigned short f2bf(float x) {
    unsigned u = __float_as_uint(x);
    unsigned r = (u + 0x7FFFu + ((u >> 16) & 1u)) >> 16;   // RNE
    return (unsigned short)r;
}
__device__ __forceinline__ float bf2f(unsigned short h) {
    return __uint_as_float(((unsigned)h) << 16);
}

// ---------------------------------------------------------------- k_prep ----
__global__ void k_prep(const float* __restrict__ emb, float* __restrict__ enorm,
                       short* __restrict__ ehi, short* __restrict__ elo,
                       unsigned int* __restrict__ hist, unsigned int* __restrict__ counter) {
    int gid = blockIdx.x * 256 + threadIdx.x;        // 0..16383
    float4 v = *(const float4*)(emb + gid * 4);
    float s = v.x * v.x + v.y * v.y + v.z * v.z + v.w * v.w;
#pragma unroll
    for (int off = 1; off < 16; off <<= 1) s += __shfl_xor(s, off, 64);
    if ((gid & 15) == 0) enorm[gid >> 4] = s;        // k = gid/16

    float vv[4] = {v.x, v.y, v.z, v.w};
    short h[4], l[4];
#pragma unroll
    for (int j = 0; j < 4; ++j) {
        unsigned short hh = f2bf(vv[j]);
        h[j] = (short)hh;
        l[j] = (short)f2bf(vv[j] - bf2f(hh));
    }
    *(short4*)&ehi[gid * 4] = make_short4(h[0], h[1], h[2], h[3]);
    *(short4*)&elo[gid * 4] = make_short4(l[0], l[1], l[2], l[3]);

    if (gid < K_CODES) hist[gid] = 0u;
    if (gid == 0) *counter = 0u;
}

// -------------------------------------------------------------- k_argmin ----
// 256 thr = 4 waves; 64 queries x 1024 codes, bf16x3 MFMA.
// Software-pipelined e-staging (regs prefetch next chunk during compute),
// enorm in LDS, branchless top-2.
__global__ __launch_bounds__(256, 3)
void k_argmin(const float* __restrict__ x,
              const short* __restrict__ ehi, const short* __restrict__ elo,
              const float* __restrict__ enorm, int* __restrict__ out_idx,
              unsigned short* __restrict__ list, unsigned int* __restrict__ counter) {
    __shared__ __align__(16) short es[2][CHUNK * CDIM];  // 2 x 16 KB
    __shared__ __align__(16) short xs[2][QT * CDIM];     // 2 x 8 KB
    __shared__ float ens[K_CODES];                       // 4 KB

    const int tid  = threadIdx.x;
    const int lane = tid & 63;
    const int w    = tid >> 6;
    const int quad = lane >> 4;
    const int col  = lane & 15;

    const int n0  = blockIdx.x * QT;
    const int b   = n0 >> 10;
    const int hw0 = n0 & 1023;

    // stage enorm once
#pragma unroll
    for (int i = 0; i < 4; ++i) ens[i * 256 + tid] = enorm[i * 256 + tid];

    // stage x tile (transpose + hi/lo split, swizzled)
#pragma unroll
    for (int p = 0; p < 4; ++p) {
        int c  = p * 16 + (tid >> 4);
        int q0 = (tid & 15) * 4;
        float4 v = *(const float4*)(x + b * (CDIM * HW_SZ) + c * HW_SZ + hw0 + q0);
        float vv[4] = {v.x, v.y, v.z, v.w};
#pragma unroll
        for (int j = 0; j < 4; ++j) {
            int q = q0 + j;
            unsigned short h = f2bf(vv[j]);
            unsigned short l = f2bf(vv[j] - bf2f(h));
            int off = q * CDIM + (((c >> 3) ^ (q & 7)) << 3) + (c & 7);
            xs[0][off] = (short)h;
            xs[1][off] = (short)l;
        }
    }

    // prefetch chunk 0 e-tile into registers (overlaps xs barrier below)
    short8 pf[2][4];
#pragma unroll
    for (int i = 0; i < 4; ++i) {
        int linS = (i * 256 + tid) * 8;
        pf[0][i] = *(const short8*)&ehi[linS];
        pf[1][i] = *(const short8*)&elo[linS];
    }

    __syncthreads();

    // A fragments (register-resident)
    short8 afr[4][2][2];
#pragma unroll
    for (int rt = 0; rt < 4; ++rt) {
        int m = rt * 16 + col;
#pragma unroll
        for (int kc = 0; kc < 2; ++kc) {
            int bb  = kc * 4 + quad;
            int off = m * CDIM + ((bb ^ (m & 7)) << 3);
            afr[rt][kc][0] = *(const short8*)&xs[0][off];
            afr[rt][kc][1] = *(const short8*)&xs[1][off];
        }
    }

    float d1[16], d2[16];
    int   i1[16];
#pragma unroll
    for (int t = 0; t < 16; ++t) { d1[t] = 3.4e38f; d2[t] = 3.4e38f; i1[t] = 0; }

    for (int chunk = 0; chunk < NCHUNK; ++chunk) {
        const int cb = chunk * CHUNK;
        __syncthreads();   // previous chunk's es reads complete
        // commit prefetched regs -> LDS (swizzled)
#pragma unroll
        for (int i = 0; i < 4; ++i) {
            int linS = (i * 256 + tid) * 8;
            int row  = linS >> 6;
            int bb   = (linS & 63) >> 3;
            int dst  = row * CDIM + ((bb ^ (row & 7)) << 3);
            *(short8*)&es[0][dst] = pf[0][i];
            *(short8*)&es[1][dst] = pf[1][i];
        }
        // issue next chunk's loads (latency hidden behind this chunk's compute)
        if (chunk + 1 < NCHUNK) {
            const int nb = (chunk + 1) * CHUNK * CDIM;
#pragma unroll
            for (int i = 0; i < 4; ++i) {
                int linS = (i * 256 + tid) * 8;
                pf[0][i] = *(const short8*)&ehi[nb + linS];
                pf[1][i] = *(const short8*)&elo[nb + linS];
            }
        }
        __syncthreads();

#pragma unroll
        for (int ct = 0; ct < 2; ++ct) {
            const int r0 = w * 32 + ct * 16;
            const int r  = r0 + col;
            short8 bfr[2][2];
#pragma unroll
            for (int kc = 0; kc < 2; ++kc) {
                int bb  = kc * 4 + quad;
                int off = r * CDIM + ((bb ^ (r & 7)) << 3);
                bfr[kc][0] = *(const short8*)&es[0][off];
                bfr[kc][1] = *(const short8*)&es[1][off];
            }
            const int mycode = cb + r;
            const float en   = ens[mycode];   // LDS, not VMEM
#pragma unroll
            for (int rt = 0; rt < 4; ++rt) {
                f32x4 acc = {0.f, 0.f, 0.f, 0.f};
                acc = __builtin_amdgcn_mfma_f32_16x16x32_bf16(afr[rt][0][1], bfr[0][0], acc, 0, 0, 0);
                acc = __builtin_amdgcn_mfma_f32_16x16x32_bf16(afr[rt][0][0], bfr[0][1], acc, 0, 0, 0);
                acc = __builtin_amdgcn_mfma_f32_16x16x32_bf16(afr[rt][0][0], bfr[0][0], acc, 0, 0, 0);
                acc = __builtin_amdgcn_mfma_f32_16x16x32_bf16(afr[rt][1][1], bfr[1][0], acc, 0, 0, 0);
                acc = __builtin_amdgcn_mfma_f32_16x16x32_bf16(afr[rt][1][0], bfr[1][1], acc, 0, 0, 0);
                acc = __builtin_amdgcn_mfma_f32_16x16x32_bf16(afr[rt][1][0], bfr[1][0], acc, 0, 0, 0);
                // branchless top-2 update
#pragma unroll
                for (int reg = 0; reg < 4; ++reg) {
                    int t = rt * 4 + reg;
                    float d   = __builtin_fmaf(acc[reg], -2.f, en);
                    float d1o = d1[t];
                    float lo  = fminf(d, d1o);
                    float hi  = fmaxf(d, d1o);
                    i1[t] = (d < d1o) ? mycode : i1[t];
                    d1[t] = lo;
                    d2[t] = fmaxf(lo, fminf(hi, d2[t]));   // med3(d, d1o, d2o)
                }
            }
        }
    }

#pragma unroll
    for (int t = 0; t < 16; ++t) {
        float a1 = d1[t], a2 = d2[t];
        int ai = i1[t];
#pragma unroll
        for (int off = 1; off < 16; off <<= 1) {
            float o1 = __shfl_xor(a1, off, 64);
            float o2 = __shfl_xor(a2, off, 64);
            int   oi = __shfl_xor(ai, off, 64);
            if (o1 < a1 || (o1 == a1 && oi < ai)) {
                float loser = a1; a2 = fminf(fminf(a2, o2), loser); a1 = o1; ai = oi;
            } else {
                a2 = fminf(fminf(a2, o2), o1);
            }
        }
        d1[t] = a1; d2[t] = a2; i1[t] = ai;
    }

    float* rd1 = (float*)xs;
    float* rd2 = rd1 + 256;
    int*   ri  = (int*)(rd2 + 256);
    __syncthreads();
    if (col == 0) {
#pragma unroll
        for (int rt = 0; rt < 4; ++rt)
#pragma unroll
            for (int reg = 0; reg < 4; ++reg) {
                int t = rt * 4 + reg;
                int m = rt * 16 + quad * 4 + reg;
                rd1[w * QT + m] = d1[t];
                rd2[w * QT + m] = d2[t];
                ri [w * QT + m] = i1[t];
            }
    }
    __syncthreads();

    if (tid < QT) {
        float a1 = rd1[tid], a2 = rd2[tid];
        int ai = ri[tid];
#pragma unroll
        for (int ww = 1; ww < 4; ++ww) {
            float o1 = rd1[ww * QT + tid], o2 = rd2[ww * QT + tid];
            int oi = ri[ww * QT + tid];
            if (o1 < a1 || (o1 == a1 && oi < ai)) {
                float loser = a1; a2 = fminf(fminf(a2, o2), loser); a1 = o1; ai = oi;
            } else {
                a2 = fminf(fminf(a2, o2), o1);
            }
        }
        out_idx[n0 + tid] = ai;
        bool flag = (a2 - a1) < TAU;
        unsigned long long mask = __ballot(flag);
        int cnt = __popcll(mask);
        unsigned base = 0;
        if (tid == 0 && cnt) base = atomicAdd(counter, (unsigned)cnt);
        base = (unsigned)__shfl((int)base, 0, 64);
        if (flag) {
            int pre = __popcll(mask & ((1ull << tid) - 1ull));
            list[base + pre] = (unsigned short)(n0 + tid);
        }
    }
}

// -------------------------------------------------------------- k_rescue ----
__global__ void k_rescue(const float* __restrict__ x, const float* __restrict__ emb,
                         const float* __restrict__ enorm,
                         const unsigned short* __restrict__ list,
                         const unsigned int* __restrict__ counter,
                         int* __restrict__ out_idx) {
    __shared__ __align__(16) float xls[CDIM];
    __shared__ float rdd[4];
    __shared__ int   rdi[4];
    const int tid  = threadIdx.x;
    const int lane = tid & 63;
    const int w    = tid >> 6;
    const unsigned cnt = *counter;

    for (unsigned qi = blockIdx.x; qi < cnt; qi += RESCUE_BLOCKS) {
        const int q  = list[qi];
        const int b  = q >> 10;
        const int hw = q & 1023;
        if (tid < CDIM) xls[tid] = x[b * (CDIM * HW_SZ) + tid * HW_SZ + hw];
        __syncthreads();

        float dmin = 3.4e38f;
        int   imin = 0;
#pragma unroll
        for (int it = 0; it < 4; ++it) {
            const int k = tid + 256 * it;
            const float4* er = (const float4*)(emb + k * CDIM);
            const float4* xr = (const float4*)xls;
            float dot = 0.f;
#pragma unroll
            for (int c4 = 0; c4 < 16; ++c4) {
                float4 e = er[c4];
                float4 xv = xr[c4];
                dot += xv.x * e.x + xv.y * e.y + xv.z * e.z + xv.w * e.w;
            }
            float d = enorm[k] - 2.f * dot;
            if (d < dmin) { dmin = d; imin = k; }
        }
#pragma unroll
        for (int off = 1; off < 64; off <<= 1) {
            float od = __shfl_xor(dmin, off, 64);
            int   oi = __shfl_xor(imin, off, 64);
            if (od < dmin || (od == dmin && oi < imin)) { dmin = od; imin = oi; }
        }
        if (lane == 0) { rdd[w] = dmin; rdi[w] = imin; }
        __syncthreads();
        if (tid == 0) {
            float bd = rdd[0]; int bi = rdi[0];
#pragma unroll
            for (int ww = 1; ww < 4; ++ww) {
                if (rdd[ww] < bd || (rdd[ww] == bd && rdi[ww] < bi)) { bd = rdd[ww]; bi = rdi[ww]; }
            }
            out_idx[q] = bi;
        }
        __syncthreads();
    }
}

// -------------------------------------------------------------- k_output ----
__global__ void k_output(const float* __restrict__ x, const float* __restrict__ emb,
                         const int* __restrict__ idx, float* __restrict__ out,
                         float* __restrict__ partials) {
    __shared__ float tile[64 * 72];   // 18 KB
    __shared__ int   ids[64];
    const int tid = threadIdx.x;
    const int n0  = blockIdx.x * 64;
    const int b   = n0 >> 10;
    const int hw0 = n0 & 1023;

    if (tid < 64) ids[tid] = idx[n0 + tid];
    __syncthreads();

    {   // gather: thread = (q = tid>>2, j = tid&3), 4 float4 each
        int q = tid >> 2, j = tid & 3;
        const float4* er = (const float4*)(emb + ids[q] * CDIM);
#pragma unroll
        for (int p = 0; p < 4; ++p) {
            float4 v = er[j * 4 + p];
            *(float4*)&tile[q * 72 + (j * 4 + p) * 4] = v;
        }
    }
    __syncthreads();

    float sse = 0.f;
    const int c = tid >> 2;
    const float* xb = x + b * (CDIM * HW_SZ) + c * HW_SZ + hw0;
    float*       ob = out + b * (CDIM * HW_SZ) + c * HW_SZ + hw0;
#pragma unroll
    for (int p = 0; p < 4; ++p) {
        int q = ((tid & 3) + p * 4) * 4;   // 0..60
        float4 v;
        v.x = tile[(q + 0) * 72 + c];
        v.y = tile[(q + 1) * 72 + c];
        v.z = tile[(q + 2) * 72 + c];
        v.w = tile[(q + 3) * 72 + c];
        float4 xv = *(const float4*)&xb[q];
        *(float4*)&ob[q] = v;
        float dx = v.x - xv.x, dy = v.y - xv.y, dz = v.z - xv.z, dw = v.w - xv.w;
        sse += dx * dx + dy * dy + dz * dz + dw * dw;
    }

    __shared__ float red[4];
#pragma unroll
    for (int off = 32; off; off >>= 1) sse += __shfl_down(sse, off, 64);
    if ((tid & 63) == 0) red[tid >> 6] = sse;
    __syncthreads();
    if (tid == 0) partials[blockIdx.x] = red[0] + red[1] + red[2] + red[3];
}

// ---------------------------------------------------------------- k_hist ----
__global__ void k_hist(const int* __restrict__ idx, unsigned int* __restrict__ hist) {
    __shared__ unsigned int lh[K_CODES];
    int tid = threadIdx.x;
#pragma unroll
    for (int i = 0; i < 4; ++i) lh[i * 256 + tid] = 0u;
    __syncthreads();
    for (int i = blockIdx.x * 256 + tid; i < N_TOTAL; i += 64 * 256)
        atomicAdd(&lh[idx[i]], 1u);
    __syncthreads();
#pragma unroll
    for (int i = 0; i < 4; ++i) {
        unsigned int v = lh[i * 256 + tid];
        if (v) atomicAdd(&hist[i * 256 + tid], v);
    }
}

// --------------------------------------------------------------- k_final ----
__global__ void k_final(const unsigned int* __restrict__ hist,
                        const float* __restrict__ partials, float* __restrict__ out2) {
    int tid = threadIdx.x;   // 256
    float ss = 0.f;
#pragma unroll
    for (int i = 0; i < 4; ++i) ss += partials[i * 256 + tid];
    float s = 0.f;
#pragma unroll
    for (int i = 0; i < 4; ++i) {
        float p = (float)hist[i * 256 + tid] * (1.0f / 65536.0f);
        s += p * logf(p + 1e-10f);
    }
    __shared__ float redA[4], redB[4];
#pragma unroll
    for (int off = 32; off; off >>= 1) {
        s  += __shfl_down(s, off, 64);
        ss += __shfl_down(ss, off, 64);
    }
    if ((tid & 63) == 0) { redA[tid >> 6] = s; redB[tid >> 6] = ss; }
    __syncthreads();
    if (tid == 0) {
        float tot = redA[0] + redA[1] + redA[2] + redA[3];
        float sse = redB[0] + redB[1] + redB[2] + redB[3];
        out2[0] = 1.25f * sse * (1.0f / (float)OUT_ELEMS);
        out2[1] = expf(-tot);
    }
}

// ---------------------------------------------------------------- launch ----
extern "C" void kernel_launch(void* const* d_in, const int* in_sizes, int n_in,
                              void* d_out, int out_size, void* d_ws, size_t ws_size,
                              hipStream_t stream) {
    const float* x   = (const float*)d_in[0];
    const float* emb = (const float*)d_in[1];
    float* out = (float*)d_out;
    char* ws = (char*)d_ws;
    float*          enorm    = (float*)(ws);
    unsigned int*   hist     = (unsigned int*)(ws + 4096);
    unsigned int*   counter  = (unsigned int*)(ws + 8192);
    short*          ehi      = (short*)(ws + 12288);
    short*          elo      = (short*)(ws + 143360);
    int*            idx      = (int*)(ws + 274432);
    unsigned short* list     = (unsigned short*)(ws + 536576);
    float*          partials = (float*)(ws + 664576);

    k_prep  <<<64, 256, 0, stream>>>(emb, enorm, ehi, elo, hist, counter);
    k_argmin<<<N_TOTAL / QT, 256, 0, stream>>>(x, ehi, elo, enorm, idx, list, counter);
    k_rescue<<<RESCUE_BLOCKS, 256, 0, stream>>>(x, emb, enorm, list, counter, idx);
    k_output<<<N_TOTAL / 64, 256, 0, stream>>>(x, emb, idx, out, partials);
    k_hist  <<<64, 256, 0, stream>>>(idx, hist);
    k_final <<<1, 256, 0, stream>>>(hist, partials, out + OUT_ELEMS);
}

// Round 7
// 195.224 us; speedup vs baseline: 1.4992x; 1.4992x over previous
//
#include <hip/hip_runtime.h>

// Problem constants
#define N_TOTAL   65536   // B*H*W = 64*32*32
#define HW_SZ     1024    // H*W
#define CDIM      64      // embedding dim (= C)
#define K_CODES   1024
#define OUT_ELEMS 4194304 // 64*64*32*32
#define QT        64      // queries per argmin block
#define CHUNK     64      // codes staged per LDS chunk (double-buffered)
#define NCHUNK    (K_CODES / CHUNK)   // 16
#define TAU       0.02f   // rescue margin (>=30x the worst-case bf16x3 error)
#define RESCUE_BLOCKS 2048

// ws layout (bytes):
//   0      : enorm[1024]  float
//   4096   : hist[1024]   uint
//   8192   : counter      uint
//   12288  : e_hi[1024*64] bf16-as-short
//   143360 : e_lo[1024*64] bf16-as-short
//   274432 : idx[65536]   int
//   536576 : list[65536]  ushort (flagged queries)
//   664576 : partials[1024] float

typedef __attribute__((ext_vector_type(8))) short short8;
typedef __attribute__((ext_vector_type(4))) float f32x4;

__device__ __forceinline__ unsigned short f2bf(float x) {
    unsigned u = __float_as_uint(x);
    unsigned r = (u + 0x7FFFu + ((u >> 16) & 1u)) >> 16;   // RNE
    return (unsigned short)r;
}
__device__ __forceinline__ float bf2f(unsigned short h) {
    return __uint_as_float(((unsigned)h) << 16);
}
// async global->LDS, 16B per lane; LDS dest = wave-uniform base + lane*16
__device__ __forceinline__ void gload_lds16(const void* g, void* l) {
    __builtin_amdgcn_global_load_lds(
        (const __attribute__((address_space(1))) void*)g,
        (__attribute__((address_space(3))) void*)l, 16, 0, 0);
}

// ---------------------------------------------------------------- k_prep ----
__global__ void k_prep(const float* __restrict__ emb, float* __restrict__ enorm,
                       short* __restrict__ ehi, short* __restrict__ elo,
                       unsigned int* __restrict__ hist, unsigned int* __restrict__ counter) {
    int gid = blockIdx.x * 256 + threadIdx.x;        // 0..16383
    float4 v = *(const float4*)(emb + gid * 4);
    float s = v.x * v.x + v.y * v.y + v.z * v.z + v.w * v.w;
#pragma unroll
    for (int off = 1; off < 16; off <<= 1) s += __shfl_xor(s, off, 64);
    if ((gid & 15) == 0) enorm[gid >> 4] = s;        // k = gid/16

    float vv[4] = {v.x, v.y, v.z, v.w};
    short h[4], l[4];
#pragma unroll
    for (int j = 0; j < 4; ++j) {
        unsigned short hh = f2bf(vv[j]);
        h[j] = (short)hh;
        l[j] = (short)f2bf(vv[j] - bf2f(hh));
    }
    *(short4*)&ehi[gid * 4] = make_short4(h[0], h[1], h[2], h[3]);
    *(short4*)&elo[gid * 4] = make_short4(l[0], l[1], l[2], l[3]);

    if (gid < K_CODES) hist[gid] = 0u;
    if (gid == 0) *counter = 0u;
}

// -------------------------------------------------------------- k_argmin ----
// 256 thr = 4 waves; 64 queries x 1024 codes, bf16x3 MFMA.
// Double-buffered async e-staging via global_load_lds (no staging VGPRs):
//   barrier -> issue prefetch(chunk+1, buf^1) -> compute(chunk, buf).
// The vmcnt(0) at each barrier waits a prefetch that had a full compute
// phase in flight; the fresh prefetch is issued after the barrier.
__global__ __launch_bounds__(256, 3)
void k_argmin(const float* __restrict__ x,
              const short* __restrict__ ehi, const short* __restrict__ elo,
              const float* __restrict__ enorm, int* __restrict__ out_idx,
              unsigned short* __restrict__ list, unsigned int* __restrict__ counter) {
    __shared__ __align__(16) short es[2][2][CHUNK * CDIM];  // [buf][hi/lo] 4x8 KB
    __shared__ __align__(16) short xs[2][QT * CDIM];        // 2 x 8 KB
    __shared__ float ens[K_CODES];                          // 4 KB

    const int tid  = threadIdx.x;
    const int lane = tid & 63;
    const int w    = tid >> 6;
    const int quad = lane >> 4;
    const int col  = lane & 15;

    const int n0  = blockIdx.x * QT;
    const int b   = n0 >> 10;
    const int hw0 = n0 & 1023;

    // async-stage one chunk (hi+lo, 16 KB) with swizzle folded into gather:
    // LDS 16B-slot s (row=s>>3, bb=s&7) <- global block (bb ^ (row&7)).
    // Per wave-issue: 8 consecutive 128B rows, fully coalesced.
    auto stage_async = [&](int chunk, int buf) {
        const int cbS = chunk * (CHUNK * CDIM);   // shorts
#pragma unroll
        for (int h = 0; h < 2; ++h) {
            const short* tab = h ? elo : ehi;
#pragma unroll
            for (int i = 0; i < 2; ++i) {
                int s   = i * 256 + w * 64 + lane;
                int row = s >> 3, bb = s & 7;
                int g   = bb ^ (row & 7);
                gload_lds16(&tab[cbS + row * 64 + g * 8],
                            (void*)&es[buf][h][(i * 256 + w * 64) * 8]);
            }
        }
    };

    // stage enorm once
#pragma unroll
    for (int i = 0; i < 4; ++i) ens[i * 256 + tid] = enorm[i * 256 + tid];

    // stage x tile (transpose + hi/lo split, swizzled)
#pragma unroll
    for (int p = 0; p < 4; ++p) {
        int c  = p * 16 + (tid >> 4);
        int q0 = (tid & 15) * 4;
        float4 v = *(const float4*)(x + b * (CDIM * HW_SZ) + c * HW_SZ + hw0 + q0);
        float vv[4] = {v.x, v.y, v.z, v.w};
#pragma unroll
        for (int j = 0; j < 4; ++j) {
            int q = q0 + j;
            unsigned short h = f2bf(vv[j]);
            unsigned short l = f2bf(vv[j] - bf2f(h));
            int off = q * CDIM + (((c >> 3) ^ (q & 7)) << 3) + (c & 7);
            xs[0][off] = (short)h;
            xs[1][off] = (short)l;
        }
    }

    // kick off chunk 0 into buffer 0 (async, no VGPRs held)
    stage_async(0, 0);

    __syncthreads();   // xs visible + chunk 0 landed

    // A fragments (register-resident)
    short8 afr[4][2][2];
#pragma unroll
    for (int rt = 0; rt < 4; ++rt) {
        int m = rt * 16 + col;
#pragma unroll
        for (int kc = 0; kc < 2; ++kc) {
            int bb  = kc * 4 + quad;
            int off = m * CDIM + ((bb ^ (m & 7)) << 3);
            afr[rt][kc][0] = *(const short8*)&xs[0][off];
            afr[rt][kc][1] = *(const short8*)&xs[1][off];
        }
    }

    float d1[16], d2[16];
    int   i1[16];
#pragma unroll
    for (int t = 0; t < 16; ++t) { d1[t] = 3.4e38f; d2[t] = 3.4e38f; i1[t] = 0; }

    for (int chunk = 0; chunk < NCHUNK; ++chunk) {
        const int buf = chunk & 1;
        if (chunk) __syncthreads();   // this chunk's prefetch + all buf^1 reads done
        if (chunk + 1 < NCHUNK) stage_async(chunk + 1, buf ^ 1);

        // compute chunk: wave owns 16 codes r = w*16 + col
        const int r  = w * 16 + col;
        short8 bfr[2][2];
#pragma unroll
        for (int kc = 0; kc < 2; ++kc) {
            int bb  = kc * 4 + quad;
            int off = r * CDIM + ((bb ^ (r & 7)) << 3);
            bfr[kc][0] = *(const short8*)&es[buf][0][off];
            bfr[kc][1] = *(const short8*)&es[buf][1][off];
        }
        const int mycode = chunk * CHUNK + r;
        const float en   = ens[mycode];
#pragma unroll
        for (int rt = 0; rt < 4; ++rt) {
            f32x4 acc = {0.f, 0.f, 0.f, 0.f};
            acc = __builtin_amdgcn_mfma_f32_16x16x32_bf16(afr[rt][0][1], bfr[0][0], acc, 0, 0, 0);
            acc = __builtin_amdgcn_mfma_f32_16x16x32_bf16(afr[rt][0][0], bfr[0][1], acc, 0, 0, 0);
            acc = __builtin_amdgcn_mfma_f32_16x16x32_bf16(afr[rt][0][0], bfr[0][0], acc, 0, 0, 0);
            acc = __builtin_amdgcn_mfma_f32_16x16x32_bf16(afr[rt][1][1], bfr[1][0], acc, 0, 0, 0);
            acc = __builtin_amdgcn_mfma_f32_16x16x32_bf16(afr[rt][1][0], bfr[1][1], acc, 0, 0, 0);
            acc = __builtin_amdgcn_mfma_f32_16x16x32_bf16(afr[rt][1][0], bfr[1][0], acc, 0, 0, 0);
            // branchless top-2 update
#pragma unroll
            for (int reg = 0; reg < 4; ++reg) {
                int t = rt * 4 + reg;
                float d   = __builtin_fmaf(acc[reg], -2.f, en);
                float d1o = d1[t];
                float lo  = fminf(d, d1o);
                float hi  = fmaxf(d, d1o);
                i1[t] = (d < d1o) ? mycode : i1[t];
                d1[t] = lo;
                d2[t] = fmaxf(lo, fminf(hi, d2[t]));   // med3(d, d1o, d2o)
            }
        }
    }

    // reduce across the 16 cols (codes) per query row
#pragma unroll
    for (int t = 0; t < 16; ++t) {
        float a1 = d1[t], a2 = d2[t];
        int ai = i1[t];
#pragma unroll
        for (int off = 1; off < 16; off <<= 1) {
            float o1 = __shfl_xor(a1, off, 64);
            float o2 = __shfl_xor(a2, off, 64);
            int   oi = __shfl_xor(ai, off, 64);
            if (o1 < a1 || (o1 == a1 && oi < ai)) {
                float loser = a1; a2 = fminf(fminf(a2, o2), loser); a1 = o1; ai = oi;
            } else {
                a2 = fminf(fminf(a2, o2), o1);
            }
        }
        d1[t] = a1; d2[t] = a2; i1[t] = ai;
    }

    float* rd1 = (float*)xs;
    float* rd2 = rd1 + 256;
    int*   ri  = (int*)(rd2 + 256);
    __syncthreads();
    if (col == 0) {
#pragma unroll
        for (int rt = 0; rt < 4; ++rt)
#pragma unroll
            for (int reg = 0; reg < 4; ++reg) {
                int t = rt * 4 + reg;
                int m = rt * 16 + quad * 4 + reg;
                rd1[w * QT + m] = d1[t];
                rd2[w * QT + m] = d2[t];
                ri [w * QT + m] = i1[t];
            }
    }
    __syncthreads();

    if (tid < QT) {
        float a1 = rd1[tid], a2 = rd2[tid];
        int ai = ri[tid];
#pragma unroll
        for (int ww = 1; ww < 4; ++ww) {
            float o1 = rd1[ww * QT + tid], o2 = rd2[ww * QT + tid];
            int oi = ri[ww * QT + tid];
            if (o1 < a1 || (o1 == a1 && oi < ai)) {
                float loser = a1; a2 = fminf(fminf(a2, o2), loser); a1 = o1; ai = oi;
            } else {
                a2 = fminf(fminf(a2, o2), o1);
            }
        }
        out_idx[n0 + tid] = ai;
        bool flag = (a2 - a1) < TAU;
        unsigned long long mask = __ballot(flag);
        int cnt = __popcll(mask);
        unsigned base = 0;
        if (tid == 0 && cnt) base = atomicAdd(counter, (unsigned)cnt);
        base = (unsigned)__shfl((int)base, 0, 64);
        if (flag) {
            int pre = __popcll(mask & ((1ull << tid) - 1ull));
            list[base + pre] = (unsigned short)(n0 + tid);
        }
    }
}

// -------------------------------------------------------------- k_rescue ----
__global__ void k_rescue(const float* __restrict__ x, const float* __restrict__ emb,
                         const float* __restrict__ enorm,
                         const unsigned short* __restrict__ list,
                         const unsigned int* __restrict__ counter,
                         int* __restrict__ out_idx) {
    __shared__ __align__(16) float xls[CDIM];
    __shared__ float rdd[4];
    __shared__ int   rdi[4];
    const int tid  = threadIdx.x;
    const int lane = tid & 63;
    const int w    = tid >> 6;
    const unsigned cnt = *counter;

    for (unsigned qi = blockIdx.x; qi < cnt; qi += RESCUE_BLOCKS) {
        const int q  = list[qi];
        const int b  = q >> 10;
        const int hw = q & 1023;
        if (tid < CDIM) xls[tid] = x[b * (CDIM * HW_SZ) + tid * HW_SZ + hw];
        __syncthreads();

        float dmin = 3.4e38f;
        int   imin = 0;
#pragma unroll
        for (int it = 0; it < 4; ++it) {
            const int k = tid + 256 * it;
            const float4* er = (const float4*)(emb + k * CDIM);
            const float4* xr = (const float4*)xls;
            float dot = 0.f;
#pragma unroll
            for (int c4 = 0; c4 < 16; ++c4) {
                float4 e = er[c4];
                float4 xv = xr[c4];
                dot += xv.x * e.x + xv.y * e.y + xv.z * e.z + xv.w * e.w;
            }
            float d = enorm[k] - 2.f * dot;
            if (d < dmin) { dmin = d; imin = k; }
        }
#pragma unroll
        for (int off = 1; off < 64; off <<= 1) {
            float od = __shfl_xor(dmin, off, 64);
            int   oi = __shfl_xor(imin, off, 64);
            if (od < dmin || (od == dmin && oi < imin)) { dmin = od; imin = oi; }
        }
        if (lane == 0) { rdd[w] = dmin; rdi[w] = imin; }
        __syncthreads();
        if (tid == 0) {
            float bd = rdd[0]; int bi = rdi[0];
#pragma unroll
            for (int ww = 1; ww < 4; ++ww) {
                if (rdd[ww] < bd || (rdd[ww] == bd && rdi[ww] < bi)) { bd = rdd[ww]; bi = rdi[ww]; }
            }
            out_idx[q] = bi;
        }
        __syncthreads();
    }
}

// -------------------------------------------------------------- k_output ----
__global__ void k_output(const float* __restrict__ x, const float* __restrict__ emb,
                         const int* __restrict__ idx, float* __restrict__ out,
                         float* __restrict__ partials) {
    __shared__ float tile[64 * 72];   // 18 KB
    __shared__ int   ids[64];
    const int tid = threadIdx.x;
    const int n0  = blockIdx.x * 64;
    const int b   = n0 >> 10;
    const int hw0 = n0 & 1023;

    if (tid < 64) ids[tid] = idx[n0 + tid];
    __syncthreads();

    {   // gather: thread = (q = tid>>2, j = tid&3), 4 float4 each
        int q = tid >> 2, j = tid & 3;
        const float4* er = (const float4*)(emb + ids[q] * CDIM);
#pragma unroll
        for (int p = 0; p < 4; ++p) {
            float4 v = er[j * 4 + p];
            *(float4*)&tile[q * 72 + (j * 4 + p) * 4] = v;
        }
    }
    __syncthreads();

    float sse = 0.f;
    const int c = tid >> 2;
    const float* xb = x + b * (CDIM * HW_SZ) + c * HW_SZ + hw0;
    float*       ob = out + b * (CDIM * HW_SZ) + c * HW_SZ + hw0;
#pragma unroll
    for (int p = 0; p < 4; ++p) {
        int q = ((tid & 3) + p * 4) * 4;   // 0..60
        float4 v;
        v.x = tile[(q + 0) * 72 + c];
        v.y = tile[(q + 1) * 72 + c];
        v.z = tile[(q + 2) * 72 + c];
        v.w = tile[(q + 3) * 72 + c];
        float4 xv = *(const float4*)&xb[q];
        *(float4*)&ob[q] = v;
        float dx = v.x - xv.x, dy = v.y - xv.y, dz = v.z - xv.z, dw = v.w - xv.w;
        sse += dx * dx + dy * dy + dz * dz + dw * dw;
    }

    __shared__ float red[4];
#pragma unroll
    for (int off = 32; off; off >>= 1) sse += __shfl_down(sse, off, 64);
    if ((tid & 63) == 0) red[tid >> 6] = sse;
    __syncthreads();
    if (tid == 0) partials[blockIdx.x] = red[0] + red[1] + red[2] + red[3];
}

// ---------------------------------------------------------------- k_hist ----
__global__ void k_hist(const int* __restrict__ idx, unsigned int* __restrict__ hist) {
    __shared__ unsigned int lh[K_CODES];
    int tid = threadIdx.x;
#pragma unroll
    for (int i = 0; i < 4; ++i) lh[i * 256 + tid] = 0u;
    __syncthreads();
    for (int i = blockIdx.x * 256 + tid; i < N_TOTAL; i += 64 * 256)
        atomicAdd(&lh[idx[i]], 1u);
    __syncthreads();
#pragma unroll
    for (int i = 0; i < 4; ++i) {
        unsigned int v = lh[i * 256 + tid];
        if (v) atomicAdd(&hist[i * 256 + tid], v);
    }
}

// --------------------------------------------------------------- k_final ----
__global__ void k_final(const unsigned int* __restrict__ hist,
                        const float* __restrict__ partials, float* __restrict__ out2) {
    int tid = threadIdx.x;   // 256
    float ss = 0.f;
#pragma unroll
    for (int i = 0; i < 4; ++i) ss += partials[i * 256 + tid];
    float s = 0.f;
#pragma unroll
    for (int i = 0; i < 4; ++i) {
        float p = (float)hist[i * 256 + tid] * (1.0f / 65536.0f);
        s += p * logf(p + 1e-10f);
    }
    __shared__ float redA[4], redB[4];
#pragma unroll
    for (int off = 32; off; off >>= 1) {
        s  += __shfl_down(s, off, 64);
        ss += __shfl_down(ss, off, 64);
    }
    if ((tid & 63) == 0) { redA[tid >> 6] = s; redB[tid >> 6] = ss; }
    __syncthreads();
    if (tid == 0) {
        float tot = redA[0] + redA[1] + redA[2] + redA[3];
        float sse = redB[0] + redB[1] + redB[2] + redB[3];
        out2[0] = 1.25f * sse * (1.0f / (float)OUT_ELEMS);
        out2[1] = expf(-tot);
    }
}

// ---------------------------------------------------------------- launch ----
extern "C" void kernel_launch(void* const* d_in, const int* in_sizes, int n_in,
                              void* d_out, int out_size, void* d_ws, size_t ws_size,
                              hipStream_t stream) {
    const float* x   = (const float*)d_in[0];
    const float* emb = (const float*)d_in[1];
    float* out = (float*)d_out;
    char* ws = (char*)d_ws;
    float*          enorm    = (float*)(ws);
    unsigned int*   hist     = (unsigned int*)(ws + 4096);
    unsigned int*   counter  = (unsigned int*)(ws + 8192);
    short*          ehi      = (short*)(ws + 12288);
    short*          elo      = (short*)(ws + 143360);
    int*            idx      = (int*)(ws + 274432);
    unsigned short* list     = (unsigned short*)(ws + 536576);
    float*          partials = (float*)(ws + 664576);

    k_prep  <<<64, 256, 0, stream>>>(emb, enorm, ehi, elo, hist, counter);
    k_argmin<<<N_TOTAL / QT, 256, 0, stream>>>(x, ehi, elo, enorm, idx, list, counter);
    k_rescue<<<RESCUE_BLOCKS, 256, 0, stream>>>(x, emb, enorm, list, counter, idx);
    k_output<<<N_TOTAL / 64, 256, 0, stream>>>(x, emb, idx, out, partials);
    k_hist  <<<64, 256, 0, stream>>>(idx, hist);
    k_final <<<1, 256, 0, stream>>>(hist, partials, out + OUT_ELEMS);
}

// Round 8
// 166.872 us; speedup vs baseline: 1.7539x; 1.1699x over previous
//
#include <hip/hip_runtime.h>

// Problem constants
#define N_TOTAL   65536   // B*H*W = 64*32*32
#define HW_SZ     1024    // H*W
#define CDIM      64      // embedding dim (= C)
#define K_CODES   1024
#define OUT_ELEMS 4194304 // 64*64*32*32
#define QT        64      // queries per argmin block
#define CHUNK     64      // codes staged per LDS chunk (double-buffered)
#define NCHUNK    (K_CODES / CHUNK)   // 16
#define TAU       0.004f  // rescue margin (>=10x the ~4e-4 worst-case bf16x3 error)
#define RESCUE_BLOCKS 512
#define RQ        32      // queries per rescue block

// ws layout (bytes):
//   0      : enorm[1024]  float
//   4096   : hist[1024]   uint
//   8192   : counter      uint
//   12288  : e_hi[1024*64] bf16-as-short
//   143360 : e_lo[1024*64] bf16-as-short
//   274432 : idx[65536]   int
//   536576 : list[65536]  ushort (flagged queries)
//   664576 : partials[1024] float

typedef __attribute__((ext_vector_type(8))) short short8;
typedef __attribute__((ext_vector_type(4))) float f32x4;

__device__ __forceinline__ unsigned short f2bf(float x) {
    unsigned u = __float_as_uint(x);
    unsigned r = (u + 0x7FFFu + ((u >> 16) & 1u)) >> 16;   // RNE
    return (unsigned short)r;
}
__device__ __forceinline__ float bf2f(unsigned short h) {
    return __uint_as_float(((unsigned)h) << 16);
}
// async global->LDS, 16B per lane; LDS dest = wave-uniform base + lane*16
__device__ __forceinline__ void gload_lds16(const void* g, void* l) {
    __builtin_amdgcn_global_load_lds(
        (const __attribute__((address_space(1))) void*)g,
        (__attribute__((address_space(3))) void*)l, 16, 0, 0);
}

// ---------------------------------------------------------------- k_prep ----
__global__ void k_prep(const float* __restrict__ emb, float* __restrict__ enorm,
                       short* __restrict__ ehi, short* __restrict__ elo,
                       unsigned int* __restrict__ hist, unsigned int* __restrict__ counter) {
    int gid = blockIdx.x * 256 + threadIdx.x;        // 0..16383
    float4 v = *(const float4*)(emb + gid * 4);
    float s = v.x * v.x + v.y * v.y + v.z * v.z + v.w * v.w;
#pragma unroll
    for (int off = 1; off < 16; off <<= 1) s += __shfl_xor(s, off, 64);
    if ((gid & 15) == 0) enorm[gid >> 4] = s;        // k = gid/16

    float vv[4] = {v.x, v.y, v.z, v.w};
    short h[4], l[4];
#pragma unroll
    for (int j = 0; j < 4; ++j) {
        unsigned short hh = f2bf(vv[j]);
        h[j] = (short)hh;
        l[j] = (short)f2bf(vv[j] - bf2f(hh));
    }
    *(short4*)&ehi[gid * 4] = make_short4(h[0], h[1], h[2], h[3]);
    *(short4*)&elo[gid * 4] = make_short4(l[0], l[1], l[2], l[3]);

    if (gid < K_CODES) hist[gid] = 0u;
    if (gid == 0) *counter = 0u;
}

// -------------------------------------------------------------- k_argmin ----
// (frozen this round except TAU; async double-buffered staging, bf16x3 MFMA)
__global__ __launch_bounds__(256, 3)
void k_argmin(const float* __restrict__ x,
              const short* __restrict__ ehi, const short* __restrict__ elo,
              const float* __restrict__ enorm, int* __restrict__ out_idx,
              unsigned short* __restrict__ list, unsigned int* __restrict__ counter) {
    __shared__ __align__(16) short es[2][2][CHUNK * CDIM];  // [buf][hi/lo] 4x8 KB
    __shared__ __align__(16) short xs[2][QT * CDIM];        // 2 x 8 KB
    __shared__ float ens[K_CODES];                          // 4 KB

    const int tid  = threadIdx.x;
    const int lane = tid & 63;
    const int w    = tid >> 6;
    const int quad = lane >> 4;
    const int col  = lane & 15;

    const int n0  = blockIdx.x * QT;
    const int b   = n0 >> 10;
    const int hw0 = n0 & 1023;

    auto stage_async = [&](int chunk, int buf) {
        const int cbS = chunk * (CHUNK * CDIM);   // shorts
#pragma unroll
        for (int h = 0; h < 2; ++h) {
            const short* tab = h ? elo : ehi;
#pragma unroll
            for (int i = 0; i < 2; ++i) {
                int s   = i * 256 + w * 64 + lane;
                int row = s >> 3, bb = s & 7;
                int g   = bb ^ (row & 7);
                gload_lds16(&tab[cbS + row * 64 + g * 8],
                            (void*)&es[buf][h][(i * 256 + w * 64) * 8]);
            }
        }
    };

#pragma unroll
    for (int i = 0; i < 4; ++i) ens[i * 256 + tid] = enorm[i * 256 + tid];

#pragma unroll
    for (int p = 0; p < 4; ++p) {
        int c  = p * 16 + (tid >> 4);
        int q0 = (tid & 15) * 4;
        float4 v = *(const float4*)(x + b * (CDIM * HW_SZ) + c * HW_SZ + hw0 + q0);
        float vv[4] = {v.x, v.y, v.z, v.w};
#pragma unroll
        for (int j = 0; j < 4; ++j) {
            int q = q0 + j;
            unsigned short h = f2bf(vv[j]);
            unsigned short l = f2bf(vv[j] - bf2f(h));
            int off = q * CDIM + (((c >> 3) ^ (q & 7)) << 3) + (c & 7);
            xs[0][off] = (short)h;
            xs[1][off] = (short)l;
        }
    }

    stage_async(0, 0);
    __syncthreads();   // xs visible + chunk 0 landed

    short8 afr[4][2][2];
#pragma unroll
    for (int rt = 0; rt < 4; ++rt) {
        int m = rt * 16 + col;
#pragma unroll
        for (int kc = 0; kc < 2; ++kc) {
            int bb  = kc * 4 + quad;
            int off = m * CDIM + ((bb ^ (m & 7)) << 3);
            afr[rt][kc][0] = *(const short8*)&xs[0][off];
            afr[rt][kc][1] = *(const short8*)&xs[1][off];
        }
    }

    float d1[16], d2[16];
    int   i1[16];
#pragma unroll
    for (int t = 0; t < 16; ++t) { d1[t] = 3.4e38f; d2[t] = 3.4e38f; i1[t] = 0; }

    for (int chunk = 0; chunk < NCHUNK; ++chunk) {
        const int buf = chunk & 1;
        if (chunk) __syncthreads();
        if (chunk + 1 < NCHUNK) stage_async(chunk + 1, buf ^ 1);

        const int r  = w * 16 + col;
        short8 bfr[2][2];
#pragma unroll
        for (int kc = 0; kc < 2; ++kc) {
            int bb  = kc * 4 + quad;
            int off = r * CDIM + ((bb ^ (r & 7)) << 3);
            bfr[kc][0] = *(const short8*)&es[buf][0][off];
            bfr[kc][1] = *(const short8*)&es[buf][1][off];
        }
        const int mycode = chunk * CHUNK + r;
        const float en   = ens[mycode];
#pragma unroll
        for (int rt = 0; rt < 4; ++rt) {
            f32x4 acc = {0.f, 0.f, 0.f, 0.f};
            acc = __builtin_amdgcn_mfma_f32_16x16x32_bf16(afr[rt][0][1], bfr[0][0], acc, 0, 0, 0);
            acc = __builtin_amdgcn_mfma_f32_16x16x32_bf16(afr[rt][0][0], bfr[0][1], acc, 0, 0, 0);
            acc = __builtin_amdgcn_mfma_f32_16x16x32_bf16(afr[rt][0][0], bfr[0][0], acc, 0, 0, 0);
            acc = __builtin_amdgcn_mfma_f32_16x16x32_bf16(afr[rt][1][1], bfr[1][0], acc, 0, 0, 0);
            acc = __builtin_amdgcn_mfma_f32_16x16x32_bf16(afr[rt][1][0], bfr[1][1], acc, 0, 0, 0);
            acc = __builtin_amdgcn_mfma_f32_16x16x32_bf16(afr[rt][1][0], bfr[1][0], acc, 0, 0, 0);
#pragma unroll
            for (int reg = 0; reg < 4; ++reg) {
                int t = rt * 4 + reg;
                float d   = __builtin_fmaf(acc[reg], -2.f, en);
                float d1o = d1[t];
                float lo  = fminf(d, d1o);
                float hi  = fmaxf(d, d1o);
                i1[t] = (d < d1o) ? mycode : i1[t];
                d1[t] = lo;
                d2[t] = fmaxf(lo, fminf(hi, d2[t]));   // med3(d, d1o, d2o)
            }
        }
    }

#pragma unroll
    for (int t = 0; t < 16; ++t) {
        float a1 = d1[t], a2 = d2[t];
        int ai = i1[t];
#pragma unroll
        for (int off = 1; off < 16; off <<= 1) {
            float o1 = __shfl_xor(a1, off, 64);
            float o2 = __shfl_xor(a2, off, 64);
            int   oi = __shfl_xor(ai, off, 64);
            if (o1 < a1 || (o1 == a1 && oi < ai)) {
                float loser = a1; a2 = fminf(fminf(a2, o2), loser); a1 = o1; ai = oi;
            } else {
                a2 = fminf(fminf(a2, o2), o1);
            }
        }
        d1[t] = a1; d2[t] = a2; i1[t] = ai;
    }

    float* rd1 = (float*)xs;
    float* rd2 = rd1 + 256;
    int*   ri  = (int*)(rd2 + 256);
    __syncthreads();
    if (col == 0) {
#pragma unroll
        for (int rt = 0; rt < 4; ++rt)
#pragma unroll
            for (int reg = 0; reg < 4; ++reg) {
                int t = rt * 4 + reg;
                int m = rt * 16 + quad * 4 + reg;
                rd1[w * QT + m] = d1[t];
                rd2[w * QT + m] = d2[t];
                ri [w * QT + m] = i1[t];
            }
    }
    __syncthreads();

    if (tid < QT) {
        float a1 = rd1[tid], a2 = rd2[tid];
        int ai = ri[tid];
#pragma unroll
        for (int ww = 1; ww < 4; ++ww) {
            float o1 = rd1[ww * QT + tid], o2 = rd2[ww * QT + tid];
            int oi = ri[ww * QT + tid];
            if (o1 < a1 || (o1 == a1 && oi < ai)) {
                float loser = a1; a2 = fminf(fminf(a2, o2), loser); a1 = o1; ai = oi;
            } else {
                a2 = fminf(fminf(a2, o2), o1);
            }
        }
        out_idx[n0 + tid] = ai;
        bool flag = (a2 - a1) < TAU;
        unsigned long long mask = __ballot(flag);
        int cnt = __popcll(mask);
        unsigned base = 0;
        if (tid == 0 && cnt) base = atomicAdd(counter, (unsigned)cnt);
        base = (unsigned)__shfl((int)base, 0, 64);
        if (flag) {
            int pre = __popcll(mask & ((1ull << tid) - 1ull));
            list[base + pre] = (unsigned short)(n0 + tid);
        }
    }
}

// -------------------------------------------------------------- k_rescue ----
// Batched: 32 flagged queries per block, one emb sweep per 16-query chunk.
// Thread owns 4 codes; x vectors in LDS (broadcast reads); exact fp32.
__global__ __launch_bounds__(256, 2)
void k_rescue(const float* __restrict__ x, const float* __restrict__ emb,
              const float* __restrict__ enorm,
              const unsigned short* __restrict__ list,
              const unsigned int* __restrict__ counter,
              int* __restrict__ out_idx) {
    __shared__ __align__(16) float xq[RQ][72];   // 9 KB, pitch 72 (16B-aligned rows)
    __shared__ int   ids[RQ];
    __shared__ float wd[4][RQ];
    __shared__ int   wi[4][RQ];

    const int tid  = threadIdx.x;
    const int lane = tid & 63;
    const int w    = tid >> 6;
    const unsigned cnt = *counter;
    const unsigned groups = (cnt + RQ - 1) / RQ;

    // per-thread codes (fixed for whole kernel): tid + cd*256, enorm hoisted
    float en[4];
#pragma unroll
    for (int cd = 0; cd < 4; ++cd) en[cd] = enorm[tid + cd * 256];

    for (unsigned g = blockIdx.x; g < groups; g += RESCUE_BLOCKS) {
        // stage 32 x-vectors: 8 threads per query, 8 channels each
        {
            int j = tid >> 3, cpart = tid & 7;
            unsigned qi = g * RQ + j;
            if (qi < cnt) {
                int q = list[qi], b = q >> 10, hw = q & 1023;
                const float* xb = x + b * (CDIM * HW_SZ) + hw;
#pragma unroll
                for (int cc = 0; cc < 8; ++cc)
                    xq[j][cpart * 8 + cc] = xb[(cpart * 8 + cc) * HW_SZ];
            } else {
#pragma unroll
                for (int cc = 0; cc < 8; ++cc) xq[j][cpart * 8 + cc] = 0.f;
            }
            if (tid < RQ) ids[tid] = (g * RQ + tid < cnt) ? (int)list[g * RQ + tid] : 0;
        }
        __syncthreads();

#pragma unroll
        for (int qc = 0; qc < 2; ++qc) {
            float acc[4][16];
#pragma unroll
            for (int cd = 0; cd < 4; ++cd)
#pragma unroll
                for (int qq = 0; qq < 16; ++qq) acc[cd][qq] = 0.f;

            for (int k4 = 0; k4 < 16; ++k4) {
                float4 e[4];
#pragma unroll
                for (int cd = 0; cd < 4; ++cd)
                    e[cd] = *(const float4*)&emb[(tid + cd * 256) * CDIM + k4 * 4];
#pragma unroll
                for (int qq = 0; qq < 16; ++qq) {
                    float4 xv = *(const float4*)&xq[qc * 16 + qq][k4 * 4]; // broadcast
#pragma unroll
                    for (int cd = 0; cd < 4; ++cd) {
                        acc[cd][qq] += e[cd].x * xv.x + e[cd].y * xv.y
                                     + e[cd].z * xv.z + e[cd].w * xv.w;
                    }
                }
            }

            // per-query argmin: local over 4 codes, then wave lex-min reduce
#pragma unroll
            for (int qq = 0; qq < 16; ++qq) {
                float bd = 3.4e38f; int bi = 0;
#pragma unroll
                for (int cd = 0; cd < 4; ++cd) {   // codes ascending in cd
                    float d = en[cd] - 2.f * acc[cd][qq];
                    int code = tid & 255; code += cd * 256;  // = tid + cd*256
                    if (d < bd) { bd = d; bi = code; }
                }
#pragma unroll
                for (int off = 1; off < 64; off <<= 1) {
                    float od = __shfl_xor(bd, off, 64);
                    int   oi = __shfl_xor(bi, off, 64);
                    if (od < bd || (od == bd && oi < bi)) { bd = od; bi = oi; }
                }
                if (lane == 0) { wd[w][qc * 16 + qq] = bd; wi[w][qc * 16 + qq] = bi; }
            }
        }
        __syncthreads();

        if (tid < RQ) {
            float bd = wd[0][tid]; int bi = wi[0][tid];
#pragma unroll
            for (int ww = 1; ww < 4; ++ww) {
                if (wd[ww][tid] < bd || (wd[ww][tid] == bd && wi[ww][tid] < bi)) {
                    bd = wd[ww][tid]; bi = wi[ww][tid];
                }
            }
            if (g * RQ + tid < cnt) out_idx[ids[tid]] = bi;
        }
        __syncthreads();   // protect xq/ids/wd for next group
    }
}

// -------------------------------------------------------------- k_output ----
__global__ void k_output(const float* __restrict__ x, const float* __restrict__ emb,
                         const int* __restrict__ idx, float* __restrict__ out,
                         float* __restrict__ partials) {
    __shared__ float tile[64 * 72];   // 18 KB
    __shared__ int   ids[64];
    const int tid = threadIdx.x;
    const int n0  = blockIdx.x * 64;
    const int b   = n0 >> 10;
    const int hw0 = n0 & 1023;

    if (tid < 64) ids[tid] = idx[n0 + tid];
    __syncthreads();

    {   // gather: thread = (q = tid>>2, j = tid&3), 4 float4 each
        int q = tid >> 2, j = tid & 3;
        const float4* er = (const float4*)(emb + ids[q] * CDIM);
#pragma unroll
        for (int p = 0; p < 4; ++p) {
            float4 v = er[j * 4 + p];
            *(float4*)&tile[q * 72 + (j * 4 + p) * 4] = v;
        }
    }
    __syncthreads();

    float sse = 0.f;
    const int c = tid >> 2;
    const float* xb = x + b * (CDIM * HW_SZ) + c * HW_SZ + hw0;
    float*       ob = out + b * (CDIM * HW_SZ) + c * HW_SZ + hw0;
#pragma unroll
    for (int p = 0; p < 4; ++p) {
        int q = ((tid & 3) + p * 4) * 4;   // 0..60
        float4 v;
        v.x = tile[(q + 0) * 72 + c];
        v.y = tile[(q + 1) * 72 + c];
        v.z = tile[(q + 2) * 72 + c];
        v.w = tile[(q + 3) * 72 + c];
        float4 xv = *(const float4*)&xb[q];
        *(float4*)&ob[q] = v;
        float dx = v.x - xv.x, dy = v.y - xv.y, dz = v.z - xv.z, dw = v.w - xv.w;
        sse += dx * dx + dy * dy + dz * dz + dw * dw;
    }

    __shared__ float red[4];
#pragma unroll
    for (int off = 32; off; off >>= 1) sse += __shfl_down(sse, off, 64);
    if ((tid & 63) == 0) red[tid >> 6] = sse;
    __syncthreads();
    if (tid == 0) partials[blockIdx.x] = red[0] + red[1] + red[2] + red[3];
}

// ---------------------------------------------------------------- k_hist ----
__global__ void k_hist(const int* __restrict__ idx, unsigned int* __restrict__ hist) {
    __shared__ unsigned int lh[K_CODES];
    int tid = threadIdx.x;
#pragma unroll
    for (int i = 0; i < 4; ++i) lh[i * 256 + tid] = 0u;
    __syncthreads();
    for (int i = blockIdx.x * 256 + tid; i < N_TOTAL; i += 64 * 256)
        atomicAdd(&lh[idx[i]], 1u);
    __syncthreads();
#pragma unroll
    for (int i = 0; i < 4; ++i) {
        unsigned int v = lh[i * 256 + tid];
        if (v) atomicAdd(&hist[i * 256 + tid], v);
    }
}

// --------------------------------------------------------------- k_final ----
__global__ void k_final(const unsigned int* __restrict__ hist,
                        const float* __restrict__ partials, float* __restrict__ out2) {
    int tid = threadIdx.x;   // 256
    float ss = 0.f;
#pragma unroll
    for (int i = 0; i < 4; ++i) ss += partials[i * 256 + tid];
    float s = 0.f;
#pragma unroll
    for (int i = 0; i < 4; ++i) {
        float p = (float)hist[i * 256 + tid] * (1.0f / 65536.0f);
        s += p * logf(p + 1e-10f);
    }
    __shared__ float redA[4], redB[4];
#pragma unroll
    for (int off = 32; off; off >>= 1) {
        s  += __shfl_down(s, off, 64);
        ss += __shfl_down(ss, off, 64);
    }
    if ((tid & 63) == 0) { redA[tid >> 6] = s; redB[tid >> 6] = ss; }
    __syncthreads();
    if (tid == 0) {
        float tot = redA[0] + redA[1] + redA[2] + redA[3];
        float sse = redB[0] + redB[1] + redB[2] + redB[3];
        out2[0] = 1.25f * sse * (1.0f / (float)OUT_ELEMS);
        out2[1] = expf(-tot);
    }
}

// ---------------------------------------------------------------- launch ----
extern "C" void kernel_launch(void* const* d_in, const int* in_sizes, int n_in,
                              void* d_out, int out_size, void* d_ws, size_t ws_size,
                              hipStream_t stream) {
    const float* x   = (const float*)d_in[0];
    const float* emb = (const float*)d_in[1];
    float* out = (float*)d_out;
    char* ws = (char*)d_ws;
    float*          enorm    = (float*)(ws);
    unsigned int*   hist     = (unsigned int*)(ws + 4096);
    unsigned int*   counter  = (unsigned int*)(ws + 8192);
    short*          ehi      = (short*)(ws + 12288);
    short*          elo      = (short*)(ws + 143360);
    int*            idx      = (int*)(ws + 274432);
    unsigned short* list     = (unsigned short*)(ws + 536576);
    float*          partials = (float*)(ws + 664576);

    k_prep  <<<64, 256, 0, stream>>>(emb, enorm, ehi, elo, hist, counter);
    k_argmin<<<N_TOTAL / QT, 256, 0, stream>>>(x, ehi, elo, enorm, idx, list, counter);
    k_rescue<<<RESCUE_BLOCKS, 256, 0, stream>>>(x, emb, enorm, list, counter, idx);
    k_output<<<N_TOTAL / 64, 256, 0, stream>>>(x, emb, idx, out, partials);
    k_hist  <<<64, 256, 0, stream>>>(idx, hist);
    k_final <<<1, 256, 0, stream>>>(hist, partials, out + OUT_ELEMS);
}

// Round 9
// 164.961 us; speedup vs baseline: 1.7742x; 1.0116x over previous
//
#include <hip/hip_runtime.h>

// Problem constants
#define N_TOTAL   65536   // B*H*W = 64*32*32
#define HW_SZ     1024    // H*W
#define CDIM      64      // embedding dim (= C)
#define K_CODES   1024
#define OUT_ELEMS 4194304 // 64*64*32*32
#define QT        64      // queries per argmin block
#define CHUNK     32      // codes per LDS chunk (double-buffered)
#define NCHUNK    (K_CODES / CHUNK)   // 32
#define TAU       0.004f  // rescue margin (>=10x worst-case bf16x3 error)
#define RESCUE_BLOCKS 512
#define RQ        32      // queries per rescue block

// ws layout (bytes):
//   0      : enorm[1024] f32
//   4096   : hist[1024]  u32
//   8192   : counter u32 ; 8196: sse_corr f32
//   12288  : e_hi[65536] bf16-as-short (128 KB)
//   143360 : e_lo[65536] (128 KB)
//   274432 : idx[65536]  u16 (128 KB)
//   405504 : list[65536] u16 (128 KB)
//   536576 : partials[1024] f32

typedef __attribute__((ext_vector_type(8))) short short8;
typedef __attribute__((ext_vector_type(4))) float f32x4;

__device__ __forceinline__ unsigned short f2bf(float x) {
    unsigned u = __float_as_uint(x);
    return (unsigned short)((u + 0x7FFFu + ((u >> 16) & 1u)) >> 16);   // RNE
}
__device__ __forceinline__ float bf2f(unsigned short h) {
    return __uint_as_float(((unsigned)h) << 16);
}
__device__ __forceinline__ void gload_lds16(const void* g, void* l) {
    __builtin_amdgcn_global_load_lds(
        (const __attribute__((address_space(1))) void*)g,
        (__attribute__((address_space(3))) void*)l, 16, 0, 0);
}

// ---------------------------------------------------------------- k_prep ----
__global__ void k_prep(const float* __restrict__ emb, float* __restrict__ enorm,
                       short* __restrict__ ehi, short* __restrict__ elo,
                       unsigned int* __restrict__ hist, unsigned int* __restrict__ counter,
                       float* __restrict__ sse_corr) {
    int gid = blockIdx.x * 256 + threadIdx.x;        // 0..16383
    float4 v = *(const float4*)(emb + gid * 4);
    float s = v.x * v.x + v.y * v.y + v.z * v.z + v.w * v.w;
#pragma unroll
    for (int off = 1; off < 16; off <<= 1) s += __shfl_xor(s, off, 64);
    if ((gid & 15) == 0) enorm[gid >> 4] = s;

    float vv[4] = {v.x, v.y, v.z, v.w};
    short h[4], l[4];
#pragma unroll
    for (int j = 0; j < 4; ++j) {
        unsigned short hh = f2bf(vv[j]);
        h[j] = (short)hh;
        l[j] = (short)f2bf(vv[j] - bf2f(hh));
    }
    *(short4*)&ehi[gid * 4] = make_short4(h[0], h[1], h[2], h[3]);
    *(short4*)&elo[gid * 4] = make_short4(l[0], l[1], l[2], l[3]);

    if (gid < K_CODES) hist[gid] = 0u;
    if (gid == 0) { *counter = 0u; *sse_corr = 0.f; }
}

// -------------------------------------------------------------- k_argmin ----
// 256 thr = 4 waves. wave w: query-half qh=w>>1 (32 q), code-tile ct=w&1 (16 c).
// CHUNK=32 double-buffered async staging; 36.5 KB LDS -> 4 blocks/CU = exactly
// the 4 blocks/CU of work (1024 blocks / 256 CU) -> single phase, no tail.
// Fused: hist atomics, per-block SSE partial (d1 + ||x||^2, flagged excluded).
__global__ __launch_bounds__(256, 4)
void k_argmin(const float* __restrict__ x,
              const short* __restrict__ ehi, const short* __restrict__ elo,
              const float* __restrict__ enorm, unsigned short* __restrict__ out_idx,
              unsigned short* __restrict__ list, unsigned int* __restrict__ counter,
              unsigned int* __restrict__ hist, float* __restrict__ partials) {
    __shared__ __align__(16) short es[2][2][CHUNK * CDIM];  // [buf][hi/lo] 16 KB
    __shared__ __align__(16) short xs[2][QT * CDIM];        // 16 KB
    __shared__ float ens[K_CODES];                          // 4 KB
    __shared__ float xnorm[QT];

    const int tid  = threadIdx.x;
    const int lane = tid & 63;
    const int w    = tid >> 6;
    const int quad = lane >> 4;
    const int col  = lane & 15;
    const int qh   = w >> 1;
    const int ct   = w & 1;

    const int n0  = blockIdx.x * QT;
    const int b   = n0 >> 10;
    const int hw0 = n0 & 1023;

    // async-stage one chunk (hi+lo, 8 KB), swizzle folded into gather:
    // LDS 16B-slot s (row=s>>3, bb=s&7) <- global block (bb ^ (row&7)).
    auto stage_async = [&](int chunk, int buf) {
        const int cbS = chunk * (CHUNK * CDIM);
#pragma unroll
        for (int h = 0; h < 2; ++h) {
            const short* tab = h ? elo : ehi;
            int row = tid >> 3, bb = tid & 7;
            int g   = bb ^ (row & 7);
            gload_lds16(&tab[cbS + row * 64 + g * 8],
                        (void*)&es[buf][h][w * 512]);
        }
    };

    if (tid < QT) xnorm[tid] = 0.f;
#pragma unroll
    for (int i = 0; i < 4; ++i) ens[i * 256 + tid] = enorm[i * 256 + tid];
    __syncthreads();   // xnorm init visible before atomics

    // stage x tile (transpose + hi/lo split, swizzled) + accumulate ||x||^2
    float nloc[4] = {0.f, 0.f, 0.f, 0.f};
    const int q0s = (tid & 15) * 4;
#pragma unroll
    for (int p = 0; p < 4; ++p) {
        int c = p * 16 + (tid >> 4);
        float4 v = *(const float4*)(x + b * (CDIM * HW_SZ) + c * HW_SZ + hw0 + q0s);
        float vv[4] = {v.x, v.y, v.z, v.w};
#pragma unroll
        for (int j = 0; j < 4; ++j) {
            int q = q0s + j;
            unsigned short h = f2bf(vv[j]);
            unsigned short l = f2bf(vv[j] - bf2f(h));
            int off = q * CDIM + (((c >> 3) ^ (q & 7)) << 3) + (c & 7);
            xs[0][off] = (short)h;
            xs[1][off] = (short)l;
            nloc[j] += vv[j] * vv[j];
        }
    }
#pragma unroll
    for (int j = 0; j < 4; ++j) atomicAdd(&xnorm[q0s + j], nloc[j]);

    stage_async(0, 0);
    __syncthreads();   // xs + xnorm + chunk 0 landed

    // A fragments (register-resident): 2 row-tiles of this wave's query half
    short8 afr[2][2][2];
#pragma unroll
    for (int rt = 0; rt < 2; ++rt) {
        int m = qh * 32 + rt * 16 + col;
#pragma unroll
        for (int kc = 0; kc < 2; ++kc) {
            int bb  = kc * 4 + quad;
            int off = m * CDIM + ((bb ^ (m & 7)) << 3);
            afr[rt][kc][0] = *(const short8*)&xs[0][off];
            afr[rt][kc][1] = *(const short8*)&xs[1][off];
        }
    }

    float d1[8], d2[8];
    int   i1[8];
#pragma unroll
    for (int t = 0; t < 8; ++t) { d1[t] = 3.4e38f; d2[t] = 3.4e38f; i1[t] = 0; }

    for (int chunk = 0; chunk < NCHUNK; ++chunk) {
        const int buf = chunk & 1;
        if (chunk) __syncthreads();
        if (chunk + 1 < NCHUNK) stage_async(chunk + 1, buf ^ 1);

        const int r = ct * 16 + col;
        short8 bfr[2][2];
#pragma unroll
        for (int kc = 0; kc < 2; ++kc) {
            int bb  = kc * 4 + quad;
            int off = r * CDIM + ((bb ^ (r & 7)) << 3);
            bfr[kc][0] = *(const short8*)&es[buf][0][off];
            bfr[kc][1] = *(const short8*)&es[buf][1][off];
        }
        const int mycode = chunk * CHUNK + r;
        const float en   = ens[mycode];
#pragma unroll
        for (int rt = 0; rt < 2; ++rt) {
            f32x4 acc = {0.f, 0.f, 0.f, 0.f};
            acc = __builtin_amdgcn_mfma_f32_16x16x32_bf16(afr[rt][0][1], bfr[0][0], acc, 0, 0, 0);
            acc = __builtin_amdgcn_mfma_f32_16x16x32_bf16(afr[rt][0][0], bfr[0][1], acc, 0, 0, 0);
            acc = __builtin_amdgcn_mfma_f32_16x16x32_bf16(afr[rt][0][0], bfr[0][0], acc, 0, 0, 0);
            acc = __builtin_amdgcn_mfma_f32_16x16x32_bf16(afr[rt][1][1], bfr[1][0], acc, 0, 0, 0);
            acc = __builtin_amdgcn_mfma_f32_16x16x32_bf16(afr[rt][1][0], bfr[1][1], acc, 0, 0, 0);
            acc = __builtin_amdgcn_mfma_f32_16x16x32_bf16(afr[rt][1][0], bfr[1][0], acc, 0, 0, 0);
#pragma unroll
            for (int reg = 0; reg < 4; ++reg) {
                int t = rt * 4 + reg;
                float d   = __builtin_fmaf(acc[reg], -2.f, en);
                float d1o = d1[t];
                float lo  = fminf(d, d1o);
                float hi  = fmaxf(d, d1o);
                i1[t] = (d < d1o) ? mycode : i1[t];
                d1[t] = lo;
                d2[t] = fmaxf(lo, fminf(hi, d2[t]));   // med3(d, d1o, d2o)
            }
        }
    }

    // reduce across 16 cols per query row
#pragma unroll
    for (int t = 0; t < 8; ++t) {
        float a1 = d1[t], a2 = d2[t];
        int ai = i1[t];
#pragma unroll
        for (int off = 1; off < 16; off <<= 1) {
            float o1 = __shfl_xor(a1, off, 64);
            float o2 = __shfl_xor(a2, off, 64);
            int   oi = __shfl_xor(ai, off, 64);
            if (o1 < a1 || (o1 == a1 && oi < ai)) {
                float loser = a1; a2 = fminf(fminf(a2, o2), loser); a1 = o1; ai = oi;
            } else {
                a2 = fminf(fminf(a2, o2), o1);
            }
        }
        d1[t] = a1; d2[t] = a2; i1[t] = ai;
    }

    // cross code-tile merge via LDS (reuse xs)
    float* rd1 = (float*)xs;            // [2][64]
    float* rd2 = rd1 + 2 * QT;
    int*   ri  = (int*)(rd2 + 2 * QT);
    __syncthreads();
    if (col == 0) {
#pragma unroll
        for (int rt = 0; rt < 2; ++rt)
#pragma unroll
            for (int reg = 0; reg < 4; ++reg) {
                int t = rt * 4 + reg;
                int m = qh * 32 + rt * 16 + quad * 4 + reg;
                rd1[ct * QT + m] = d1[t];
                rd2[ct * QT + m] = d2[t];
                ri [ct * QT + m] = i1[t];
            }
    }
    __syncthreads();

    if (tid < QT) {   // wave 0 exactly
        float a1 = rd1[tid], a2 = rd2[tid];
        int ai = ri[tid];
        float o1 = rd1[QT + tid], o2 = rd2[QT + tid];
        int oi = ri[QT + tid];
        if (o1 < a1 || (o1 == a1 && oi < ai)) {
            float loser = a1; a2 = fminf(fminf(a2, o2), loser); a1 = o1; ai = oi;
        } else {
            a2 = fminf(fminf(a2, o2), o1);
        }
        out_idx[n0 + tid] = (unsigned short)ai;
        atomicAdd(&hist[ai], 1u);

        bool flag = (a2 - a1) < TAU;
        unsigned long long mask = __ballot(flag);
        int cnt = __popcll(mask);
        unsigned base = 0;
        if (tid == 0 && cnt) base = atomicAdd(counter, (unsigned)cnt);
        base = (unsigned)__shfl((int)base, 0, 64);
        if (flag) {
            int pre = __popcll(mask & ((1ull << tid) - 1ull));
            list[base + pre] = (unsigned short)(n0 + tid);
        }
        // SSE partial: d1 + ||x||^2 ; flagged queries contributed by rescue
        float sp = flag ? 0.f : (a1 + xnorm[tid]);
#pragma unroll
        for (int off = 32; off; off >>= 1) sp += __shfl_down(sp, off, 64);
        if (tid == 0) partials[blockIdx.x] = sp;
    }
}

// -------------------------------------------------------------- k_rescue ----
// Batched: 32 flagged queries/block, exact fp32; fixes idx, hist, sse_corr.
__global__ __launch_bounds__(256, 2)
void k_rescue(const float* __restrict__ x, const float* __restrict__ emb,
              const float* __restrict__ enorm,
              const unsigned short* __restrict__ list,
              const unsigned int* __restrict__ counter,
              unsigned short* __restrict__ out_idx,
              unsigned int* __restrict__ hist, float* __restrict__ sse_corr) {
    __shared__ __align__(16) float xq[RQ][72];
    __shared__ unsigned short ids[RQ];
    __shared__ float xn[RQ];
    __shared__ float wd[4][RQ];
    __shared__ int   wi[4][RQ];

    const int tid  = threadIdx.x;
    const int lane = tid & 63;
    const int w    = tid >> 6;
    const unsigned cnt = *counter;
    const unsigned groups = (cnt + RQ - 1) / RQ;

    float en[4];
#pragma unroll
    for (int cd = 0; cd < 4; ++cd) en[cd] = enorm[tid + cd * 256];

    for (unsigned g = blockIdx.x; g < groups; g += RESCUE_BLOCKS) {
        {
            int j = tid >> 3, cpart = tid & 7;
            unsigned qi = g * RQ + j;
            if (qi < cnt) {
                int q = list[qi], b = q >> 10, hw = q & 1023;
                const float* xb = x + b * (CDIM * HW_SZ) + hw;
#pragma unroll
                for (int cc = 0; cc < 8; ++cc)
                    xq[j][cpart * 8 + cc] = xb[(cpart * 8 + cc) * HW_SZ];
            } else {
#pragma unroll
                for (int cc = 0; cc < 8; ++cc) xq[j][cpart * 8 + cc] = 0.f;
            }
            if (tid < RQ) ids[tid] = (g * RQ + tid < cnt) ? list[g * RQ + tid] : (unsigned short)0;
        }
        __syncthreads();

        if (tid < RQ) {   // ||x||^2 of own query (same-thread read later: safe)
            float s = 0.f;
#pragma unroll
            for (int c4 = 0; c4 < 16; ++c4) {
                float4 xv = *(const float4*)&xq[tid][c4 * 4];
                s += xv.x * xv.x + xv.y * xv.y + xv.z * xv.z + xv.w * xv.w;
            }
            xn[tid] = s;
        }

#pragma unroll
        for (int qc = 0; qc < 2; ++qc) {
            float acc[4][16];
#pragma unroll
            for (int cd = 0; cd < 4; ++cd)
#pragma unroll
                for (int qq = 0; qq < 16; ++qq) acc[cd][qq] = 0.f;

            for (int k4 = 0; k4 < 16; ++k4) {
                float4 e[4];
#pragma unroll
                for (int cd = 0; cd < 4; ++cd)
                    e[cd] = *(const float4*)&emb[(tid + cd * 256) * CDIM + k4 * 4];
#pragma unroll
                for (int qq = 0; qq < 16; ++qq) {
                    float4 xv = *(const float4*)&xq[qc * 16 + qq][k4 * 4];
#pragma unroll
                    for (int cd = 0; cd < 4; ++cd) {
                        acc[cd][qq] += e[cd].x * xv.x + e[cd].y * xv.y
                                     + e[cd].z * xv.z + e[cd].w * xv.w;
                    }
                }
            }

#pragma unroll
            for (int qq = 0; qq < 16; ++qq) {
                float bd = 3.4e38f; int bi = 0;
#pragma unroll
                for (int cd = 0; cd < 4; ++cd) {
                    float d = en[cd] - 2.f * acc[cd][qq];
                    int code = tid + cd * 256;
                    if (d < bd) { bd = d; bi = code; }
                }
#pragma unroll
                for (int off = 1; off < 64; off <<= 1) {
                    float od = __shfl_xor(bd, off, 64);
                    int   oi = __shfl_xor(bi, off, 64);
                    if (od < bd || (od == bd && oi < bi)) { bd = od; bi = oi; }
                }
                if (lane == 0) { wd[w][qc * 16 + qq] = bd; wi[w][qc * 16 + qq] = bi; }
            }
        }
        __syncthreads();

        float corr = 0.f;
        if (tid < RQ && g * RQ + tid < cnt) {
            float bd = wd[0][tid]; int bi = wi[0][tid];
#pragma unroll
            for (int ww = 1; ww < 4; ++ww) {
                if (wd[ww][tid] < bd || (wd[ww][tid] == bd && wi[ww][tid] < bi)) {
                    bd = wd[ww][tid]; bi = wi[ww][tid];
                }
            }
            int q = ids[tid];
            int old = out_idx[q];
            out_idx[q] = (unsigned short)bi;
            if (bi != old) {
                atomicAdd(&hist[old], 0xFFFFFFFFu);   // -1
                atomicAdd(&hist[bi], 1u);
            }
            corr = bd + xn[tid];   // exact (q-x)^2 sum for this flagged query
        }
        if (tid < 64) {   // wave-0 reduce (lanes >=32 hold 0)
#pragma unroll
            for (int off = 32; off; off >>= 1) corr += __shfl_down(corr, off, 64);
            if (tid == 0 && corr != 0.f) atomicAdd(sse_corr, corr);
        }
        __syncthreads();
    }
}

// -------------------------------------------------------------- k_output ----
// Pure gather+write. Block 0 additionally computes loss & perplexity
// (partials/hist/sse_corr are complete before this kernel launches).
__global__ void k_output(const float* __restrict__ x, const float* __restrict__ emb,
                         const unsigned short* __restrict__ idx, float* __restrict__ out,
                         const float* __restrict__ partials,
                         const float* __restrict__ sse_corr,
                         const unsigned int* __restrict__ hist) {
    __shared__ float tile[64 * 72];   // 18 KB
    __shared__ int   ids[64];
    __shared__ float fin[8];
    const int tid = threadIdx.x;
    const int n0  = blockIdx.x * 64;
    const int b   = n0 >> 10;
    const int hw0 = n0 & 1023;

    if (tid < 64) ids[tid] = (int)idx[n0 + tid];
    __syncthreads();

    {   // gather: thread = (q = tid>>2, j = tid&3), 4 float4 each
        int q = tid >> 2, j = tid & 3;
        const float4* er = (const float4*)(emb + ids[q] * CDIM);
#pragma unroll
        for (int p = 0; p < 4; ++p)
            *(float4*)&tile[q * 72 + (j * 4 + p) * 4] = er[j * 4 + p];
    }
    __syncthreads();

    const int c = tid >> 2;
    float* ob = out + b * (CDIM * HW_SZ) + c * HW_SZ + hw0;
#pragma unroll
    for (int p = 0; p < 4; ++p) {
        int q = ((tid & 3) + p * 4) * 4;   // 0..60
        float4 v;
        v.x = tile[(q + 0) * 72 + c];
        v.y = tile[(q + 1) * 72 + c];
        v.z = tile[(q + 2) * 72 + c];
        v.w = tile[(q + 3) * 72 + c];
        *(float4*)&ob[q] = v;
    }

    if (blockIdx.x == 0) {   // fused final (block-uniform branch)
        float ss = 0.f;
#pragma unroll
        for (int i = 0; i < 4; ++i) ss += partials[i * 256 + tid];
        float s = 0.f;
#pragma unroll
        for (int i = 0; i < 4; ++i) {
            float p = (float)hist[i * 256 + tid] * (1.0f / 65536.0f);
            s += p * logf(p + 1e-10f);
        }
#pragma unroll
        for (int off = 32; off; off >>= 1) {
            ss += __shfl_down(ss, off, 64);
            s  += __shfl_down(s, off, 64);
        }
        if ((tid & 63) == 0) { fin[tid >> 6] = ss; fin[4 + (tid >> 6)] = s; }
        __syncthreads();
        if (tid == 0) {
            float sse = fin[0] + fin[1] + fin[2] + fin[3] + *sse_corr;
            float ent = fin[4] + fin[5] + fin[6] + fin[7];
            out[OUT_ELEMS]     = 1.25f * sse * (1.0f / (float)OUT_ELEMS);  // loss
            out[OUT_ELEMS + 1] = expf(-ent);                                // perplexity
        }
    }
}

// ---------------------------------------------------------------- launch ----
extern "C" void kernel_launch(void* const* d_in, const int* in_sizes, int n_in,
                              void* d_out, int out_size, void* d_ws, size_t ws_size,
                              hipStream_t stream) {
    const float* x   = (const float*)d_in[0];
    const float* emb = (const float*)d_in[1];
    float* out = (float*)d_out;
    char* ws = (char*)d_ws;
    float*          enorm    = (float*)(ws);
    unsigned int*   hist     = (unsigned int*)(ws + 4096);
    unsigned int*   counter  = (unsigned int*)(ws + 8192);
    float*          sse_corr = (float*)(ws + 8196);
    short*          ehi      = (short*)(ws + 12288);
    short*          elo      = (short*)(ws + 143360);
    unsigned short* idx      = (unsigned short*)(ws + 274432);
    unsigned short* list     = (unsigned short*)(ws + 405504);
    float*          partials = (float*)(ws + 536576);

    k_prep  <<<64, 256, 0, stream>>>(emb, enorm, ehi, elo, hist, counter, sse_corr);
    k_argmin<<<N_TOTAL / QT, 256, 0, stream>>>(x, ehi, elo, enorm, idx, list, counter, hist, partials);
    k_rescue<<<RESCUE_BLOCKS, 256, 0, stream>>>(x, emb, enorm, list, counter, idx, hist, sse_corr);
    k_output<<<N_TOTAL / 64, 256, 0, stream>>>(x, emb, idx, out, partials, sse_corr, hist);
}

// Round 10
// 163.732 us; speedup vs baseline: 1.7875x; 1.0075x over previous
//
#include <hip/hip_runtime.h>

// Problem constants
#define N_TOTAL   65536   // B*H*W = 64*32*32
#define HW_SZ     1024    // H*W
#define CDIM      64      // embedding dim (= C)
#define K_CODES   1024
#define OUT_ELEMS 4194304 // 64*64*32*32
#define QT        128     // queries per argmin block
#define CHUNK     64      // codes per LDS chunk (double-buffered)
#define NCHUNK    (K_CODES / CHUNK)   // 16
#define TAU       0.004f  // rescue margin (>=10x worst-case bf16x3 error)
#define RESCUE_BLOCKS 512
#define RQ        32      // queries per rescue block

// ws layout (bytes):
//   0      : enorm[1024] f32
//   4096   : hist[1024]  u32
//   8192   : counter u32 ; 8196: sse_corr f32
//   12288  : e_hi[65536] bf16-as-short (128 KB)
//   143360 : e_lo[65536] (128 KB)
//   274432 : idx[65536]  u16 (128 KB)
//   405504 : list[65536] u16 (128 KB)
//   536576 : partials[512] f32

typedef __attribute__((ext_vector_type(8))) short short8;
typedef __attribute__((ext_vector_type(4))) float f32x4;

__device__ __forceinline__ unsigned short f2bf(float x) {
    unsigned u = __float_as_uint(x);
    return (unsigned short)((u + 0x7FFFu + ((u >> 16) & 1u)) >> 16);   // RNE
}
__device__ __forceinline__ float bf2f(unsigned short h) {
    return __uint_as_float(((unsigned)h) << 16);
}
__device__ __forceinline__ void gload_lds16(const void* g, void* l) {
    __builtin_amdgcn_global_load_lds(
        (const __attribute__((address_space(1))) void*)g,
        (__attribute__((address_space(3))) void*)l, 16, 0, 0);
}

// ---------------------------------------------------------------- k_prep ----
__global__ void k_prep(const float* __restrict__ emb, float* __restrict__ enorm,
                       short* __restrict__ ehi, short* __restrict__ elo,
                       unsigned int* __restrict__ hist, unsigned int* __restrict__ counter,
                       float* __restrict__ sse_corr) {
    int gid = blockIdx.x * 256 + threadIdx.x;        // 0..16383
    float4 v = *(const float4*)(emb + gid * 4);
    float s = v.x * v.x + v.y * v.y + v.z * v.z + v.w * v.w;
#pragma unroll
    for (int off = 1; off < 16; off <<= 1) s += __shfl_xor(s, off, 64);
    if ((gid & 15) == 0) enorm[gid >> 4] = s;

    float vv[4] = {v.x, v.y, v.z, v.w};
    short h[4], l[4];
#pragma unroll
    for (int j = 0; j < 4; ++j) {
        unsigned short hh = f2bf(vv[j]);
        h[j] = (short)hh;
        l[j] = (short)f2bf(vv[j] - bf2f(hh));
    }
    *(short4*)&ehi[gid * 4] = make_short4(h[0], h[1], h[2], h[3]);
    *(short4*)&elo[gid * 4] = make_short4(l[0], l[1], l[2], l[3]);

    if (gid < K_CODES) hist[gid] = 0u;
    if (gid == 0) { *counter = 0u; *sse_corr = 0.f; }
}

// -------------------------------------------------------------- k_argmin ----
// 256 thr = 4 waves; QT=128 queries/block, wave w owns 32 queries (2 rt of 16)
// x ALL codes. CHUNK=64 double-buffered async staging -> 16 barriers/block,
// 48 MFMA + 32 med3 top-2 updates per wave per barrier. 68.5 KB LDS ->
// 2 blocks/CU = exactly the work per CU (512 blocks / 256 CU): single phase.
__global__ __launch_bounds__(256, 2)
void k_argmin(const float* __restrict__ x,
              const short* __restrict__ ehi, const short* __restrict__ elo,
              const float* __restrict__ enorm, unsigned short* __restrict__ out_idx,
              unsigned short* __restrict__ list, unsigned int* __restrict__ counter,
              unsigned int* __restrict__ hist, float* __restrict__ partials) {
    __shared__ __align__(16) short es[2][2][CHUNK * CDIM];  // [buf][hi/lo] 32 KB
    __shared__ __align__(16) short xs[2][QT * CDIM];        // 32 KB
    __shared__ float ens[K_CODES];                          // 4 KB
    __shared__ float xnorm[QT];
    __shared__ float spw[2];

    const int tid  = threadIdx.x;
    const int lane = tid & 63;
    const int w    = tid >> 6;        // wave = query group (32 queries)
    const int quad = lane >> 4;
    const int col  = lane & 15;

    const int n0  = blockIdx.x * QT;
    const int b   = n0 >> 10;
    const int hw0 = n0 & 1023;        // 128-aligned

    // async-stage one chunk (hi+lo, 16 KB); swizzle folded into gather:
    // LDS 16B-slot s (row=s>>3, bb=s&7) <- global block (bb ^ (row&7)).
    auto stage_async = [&](int chunk, int buf) {
        const int cbS = chunk * (CHUNK * CDIM);
#pragma unroll
        for (int h = 0; h < 2; ++h) {
            const short* tab = h ? elo : ehi;
#pragma unroll
            for (int i = 0; i < 2; ++i) {
                int s   = i * 256 + tid;
                int row = s >> 3, bb = s & 7;
                int g   = bb ^ (row & 7);
                gload_lds16(&tab[cbS + row * 64 + g * 8],
                            (void*)&es[buf][h][s * 8]);
            }
        }
    };

    if (tid < QT) xnorm[tid] = 0.f;
#pragma unroll
    for (int i = 0; i < 4; ++i) ens[i * 256 + tid] = enorm[i * 256 + tid];
    __syncthreads();   // xnorm init visible before atomics

    // stage x tile (transpose + hi/lo split, swizzled) + accumulate ||x||^2.
    // thread: fixed q-range 4*(tid&31)..+3, c = p*8 + (tid>>5), p=0..7.
    float nloc[4] = {0.f, 0.f, 0.f, 0.f};
    const int q0s = (tid & 31) * 4;
#pragma unroll
    for (int p = 0; p < 8; ++p) {
        int c = p * 8 + (tid >> 5);
        float4 v = *(const float4*)(x + b * (CDIM * HW_SZ) + c * HW_SZ + hw0 + q0s);
        float vv[4] = {v.x, v.y, v.z, v.w};
#pragma unroll
        for (int j = 0; j < 4; ++j) {
            int q = q0s + j;
            unsigned short h = f2bf(vv[j]);
            unsigned short l = f2bf(vv[j] - bf2f(h));
            int off = q * CDIM + (((c >> 3) ^ (q & 7)) << 3) + (c & 7);
            xs[0][off] = (short)h;
            xs[1][off] = (short)l;
            nloc[j] += vv[j] * vv[j];
        }
    }
#pragma unroll
    for (int j = 0; j < 4; ++j) atomicAdd(&xnorm[q0s + j], nloc[j]);

    stage_async(0, 0);
    __syncthreads();   // xs + xnorm + chunk 0 landed

    // A fragments (register-resident): wave's 2 query tiles of 16
    short8 afr[2][2][2];
#pragma unroll
    for (int rt = 0; rt < 2; ++rt) {
        int m = w * 32 + rt * 16 + col;
#pragma unroll
        for (int kc = 0; kc < 2; ++kc) {
            int bb  = kc * 4 + quad;
            int off = m * CDIM + ((bb ^ (m & 7)) << 3);
            afr[rt][kc][0] = *(const short8*)&xs[0][off];
            afr[rt][kc][1] = *(const short8*)&xs[1][off];
        }
    }

    float d1[8], d2[8];
    int   i1[8];
#pragma unroll
    for (int t = 0; t < 8; ++t) { d1[t] = 3.4e38f; d2[t] = 3.4e38f; i1[t] = 0; }

    for (int chunk = 0; chunk < NCHUNK; ++chunk) {
        const int buf = chunk & 1;
        if (chunk) __syncthreads();
        if (chunk + 1 < NCHUNK) stage_async(chunk + 1, buf ^ 1);

#pragma unroll
        for (int ct = 0; ct < 4; ++ct) {
            const int r = ct * 16 + col;
            short8 bfr[2][2];
#pragma unroll
            for (int kc = 0; kc < 2; ++kc) {
                int bb  = kc * 4 + quad;
                int off = r * CDIM + ((bb ^ (r & 7)) << 3);
                bfr[kc][0] = *(const short8*)&es[buf][0][off];
                bfr[kc][1] = *(const short8*)&es[buf][1][off];
            }
            const int mycode = chunk * CHUNK + r;
            const float en   = ens[mycode];
#pragma unroll
            for (int rt = 0; rt < 2; ++rt) {
                f32x4 acc = {0.f, 0.f, 0.f, 0.f};
                acc = __builtin_amdgcn_mfma_f32_16x16x32_bf16(afr[rt][0][1], bfr[0][0], acc, 0, 0, 0);
                acc = __builtin_amdgcn_mfma_f32_16x16x32_bf16(afr[rt][0][0], bfr[0][1], acc, 0, 0, 0);
                acc = __builtin_amdgcn_mfma_f32_16x16x32_bf16(afr[rt][0][0], bfr[0][0], acc, 0, 0, 0);
                acc = __builtin_amdgcn_mfma_f32_16x16x32_bf16(afr[rt][1][1], bfr[1][0], acc, 0, 0, 0);
                acc = __builtin_amdgcn_mfma_f32_16x16x32_bf16(afr[rt][1][0], bfr[1][1], acc, 0, 0, 0);
                acc = __builtin_amdgcn_mfma_f32_16x16x32_bf16(afr[rt][1][0], bfr[1][0], acc, 0, 0, 0);
                // 5-op branchless top-2: fma, cmp+sel, med3, min
#pragma unroll
                for (int reg = 0; reg < 4; ++reg) {
                    int t = rt * 4 + reg;
                    float d   = __builtin_fmaf(acc[reg], -2.f, en);
                    float d1o = d1[t];
                    d2[t] = __builtin_amdgcn_fmed3f(d, d1o, d2[t]);
                    d1[t] = fminf(d, d1o);
                    i1[t] = (d < d1o) ? mycode : i1[t];
                }
            }
        }
    }

    // reduce across 16 cols per query row (codes ascend with col: lex-min ok)
#pragma unroll
    for (int t = 0; t < 8; ++t) {
        float a1 = d1[t], a2 = d2[t];
        int ai = i1[t];
#pragma unroll
        for (int off = 1; off < 16; off <<= 1) {
            float o1 = __shfl_xor(a1, off, 64);
            float o2 = __shfl_xor(a2, off, 64);
            int   oi = __shfl_xor(ai, off, 64);
            if (o1 < a1 || (o1 == a1 && oi < ai)) {
                float loser = a1; a2 = fminf(fminf(a2, o2), loser); a1 = o1; ai = oi;
            } else {
                a2 = fminf(fminf(a2, o2), o1);
            }
        }
        d1[t] = a1; d2[t] = a2; i1[t] = ai;
    }

    // per-query results -> LDS (reuse xs); no cross-wave merge needed
    float* rd1 = (float*)xs;            // [128]
    float* rd2 = rd1 + QT;
    int*   ri  = (int*)(rd2 + QT);
    __syncthreads();
    if (col == 0) {
#pragma unroll
        for (int rt = 0; rt < 2; ++rt)
#pragma unroll
            for (int reg = 0; reg < 4; ++reg) {
                int t = rt * 4 + reg;
                int m = w * 32 + rt * 16 + quad * 4 + reg;
                rd1[m] = d1[t];
                rd2[m] = d2[t];
                ri [m] = i1[t];
            }
    }
    __syncthreads();

    if (tid < QT) {   // waves 0,1: finalize 128 queries
        float a1 = rd1[tid], a2 = rd2[tid];
        int ai = ri[tid];
        out_idx[n0 + tid] = (unsigned short)ai;
        atomicAdd(&hist[ai], 1u);

        bool flag = (a2 - a1) < TAU;
        unsigned long long mask = __ballot(flag);   // per-wave
        int cnt = __popcll(mask);
        unsigned base = 0;
        if (lane == 0 && cnt) base = atomicAdd(counter, (unsigned)cnt);
        base = (unsigned)__shfl((int)base, 0, 64);
        if (flag) {
            int pre = __popcll(mask & ((1ull << lane) - 1ull));
            list[base + pre] = (unsigned short)(n0 + tid);
        }
        // SSE partial: d1 + ||x||^2 ; flagged queries contributed by rescue
        float sp = flag ? 0.f : (a1 + xnorm[tid]);
#pragma unroll
        for (int off = 32; off; off >>= 1) sp += __shfl_down(sp, off, 64);
        if (lane == 0) spw[tid >> 6] = sp;
    }
    __syncthreads();
    if (tid == 0) partials[blockIdx.x] = spw[0] + spw[1];
}

// -------------------------------------------------------------- k_rescue ----
// Batched: 32 flagged queries/block, exact fp32; fixes idx, hist, sse_corr.
__global__ __launch_bounds__(256, 2)
void k_rescue(const float* __restrict__ x, const float* __restrict__ emb,
              const float* __restrict__ enorm,
              const unsigned short* __restrict__ list,
              const unsigned int* __restrict__ counter,
              unsigned short* __restrict__ out_idx,
              unsigned int* __restrict__ hist, float* __restrict__ sse_corr) {
    __shared__ __align__(16) float xq[RQ][72];
    __shared__ unsigned short ids[RQ];
    __shared__ float xn[RQ];
    __shared__ float wd[4][RQ];
    __shared__ int   wi[4][RQ];

    const int tid  = threadIdx.x;
    const int lane = tid & 63;
    const int w    = tid >> 6;
    const unsigned cnt = *counter;
    const unsigned groups = (cnt + RQ - 1) / RQ;

    float en[4];
#pragma unroll
    for (int cd = 0; cd < 4; ++cd) en[cd] = enorm[tid + cd * 256];

    for (unsigned g = blockIdx.x; g < groups; g += RESCUE_BLOCKS) {
        {
            int j = tid >> 3, cpart = tid & 7;
            unsigned qi = g * RQ + j;
            if (qi < cnt) {
                int q = list[qi], b = q >> 10, hw = q & 1023;
                const float* xb = x + b * (CDIM * HW_SZ) + hw;
#pragma unroll
                for (int cc = 0; cc < 8; ++cc)
                    xq[j][cpart * 8 + cc] = xb[(cpart * 8 + cc) * HW_SZ];
            } else {
#pragma unroll
                for (int cc = 0; cc < 8; ++cc) xq[j][cpart * 8 + cc] = 0.f;
            }
            if (tid < RQ) ids[tid] = (g * RQ + tid < cnt) ? list[g * RQ + tid] : (unsigned short)0;
        }
        __syncthreads();

        if (tid < RQ) {
            float s = 0.f;
#pragma unroll
            for (int c4 = 0; c4 < 16; ++c4) {
                float4 xv = *(const float4*)&xq[tid][c4 * 4];
                s += xv.x * xv.x + xv.y * xv.y + xv.z * xv.z + xv.w * xv.w;
            }
            xn[tid] = s;
        }

#pragma unroll
        for (int qc = 0; qc < 2; ++qc) {
            float acc[4][16];
#pragma unroll
            for (int cd = 0; cd < 4; ++cd)
#pragma unroll
                for (int qq = 0; qq < 16; ++qq) acc[cd][qq] = 0.f;

            for (int k4 = 0; k4 < 16; ++k4) {
                float4 e[4];
#pragma unroll
                for (int cd = 0; cd < 4; ++cd)
                    e[cd] = *(const float4*)&emb[(tid + cd * 256) * CDIM + k4 * 4];
#pragma unroll
                for (int qq = 0; qq < 16; ++qq) {
                    float4 xv = *(const float4*)&xq[qc * 16 + qq][k4 * 4];
#pragma unroll
                    for (int cd = 0; cd < 4; ++cd) {
                        acc[cd][qq] += e[cd].x * xv.x + e[cd].y * xv.y
                                     + e[cd].z * xv.z + e[cd].w * xv.w;
                    }
                }
            }

#pragma unroll
            for (int qq = 0; qq < 16; ++qq) {
                float bd = 3.4e38f; int bi = 0;
#pragma unroll
                for (int cd = 0; cd < 4; ++cd) {
                    float d = en[cd] - 2.f * acc[cd][qq];
                    int code = tid + cd * 256;
                    if (d < bd) { bd = d; bi = code; }
                }
#pragma unroll
                for (int off = 1; off < 64; off <<= 1) {
                    float od = __shfl_xor(bd, off, 64);
                    int   oi = __shfl_xor(bi, off, 64);
                    if (od < bd || (od == bd && oi < bi)) { bd = od; bi = oi; }
                }
                if (lane == 0) { wd[w][qc * 16 + qq] = bd; wi[w][qc * 16 + qq] = bi; }
            }
        }
        __syncthreads();

        float corr = 0.f;
        if (tid < RQ && g * RQ + tid < cnt) {
            float bd = wd[0][tid]; int bi = wi[0][tid];
#pragma unroll
            for (int ww = 1; ww < 4; ++ww) {
                if (wd[ww][tid] < bd || (wd[ww][tid] == bd && wi[ww][tid] < bi)) {
                    bd = wd[ww][tid]; bi = wi[ww][tid];
                }
            }
            int q = ids[tid];
            int old = out_idx[q];
            out_idx[q] = (unsigned short)bi;
            if (bi != old) {
                atomicAdd(&hist[old], 0xFFFFFFFFu);   // -1
                atomicAdd(&hist[bi], 1u);
            }
            corr = bd + xn[tid];   // exact (q-x)^2 sum for this flagged query
        }
        if (tid < 64) {
#pragma unroll
            for (int off = 32; off; off >>= 1) corr += __shfl_down(corr, off, 64);
            if (tid == 0 && corr != 0.f) atomicAdd(sse_corr, corr);
        }
        __syncthreads();
    }
}

// -------------------------------------------------------------- k_output ----
// Pure gather+write. Block 0 additionally computes loss & perplexity.
__global__ void k_output(const float* __restrict__ x, const float* __restrict__ emb,
                         const unsigned short* __restrict__ idx, float* __restrict__ out,
                         const float* __restrict__ partials,
                         const float* __restrict__ sse_corr,
                         const unsigned int* __restrict__ hist) {
    __shared__ float tile[64 * 72];   // 18 KB
    __shared__ int   ids[64];
    __shared__ float fin[8];
    const int tid = threadIdx.x;
    const int n0  = blockIdx.x * 64;
    const int b   = n0 >> 10;
    const int hw0 = n0 & 1023;

    if (tid < 64) ids[tid] = (int)idx[n0 + tid];
    __syncthreads();

    {   // gather: thread = (q = tid>>2, j = tid&3), 4 float4 each
        int q = tid >> 2, j = tid & 3;
        const float4* er = (const float4*)(emb + ids[q] * CDIM);
#pragma unroll
        for (int p = 0; p < 4; ++p)
            *(float4*)&tile[q * 72 + (j * 4 + p) * 4] = er[j * 4 + p];
    }
    __syncthreads();

    const int c = tid >> 2;
    float* ob = out + b * (CDIM * HW_SZ) + c * HW_SZ + hw0;
#pragma unroll
    for (int p = 0; p < 4; ++p) {
        int q = ((tid & 3) + p * 4) * 4;   // 0..60
        float4 v;
        v.x = tile[(q + 0) * 72 + c];
        v.y = tile[(q + 1) * 72 + c];
        v.z = tile[(q + 2) * 72 + c];
        v.w = tile[(q + 3) * 72 + c];
        *(float4*)&ob[q] = v;
    }

    if (blockIdx.x == 0) {   // fused final (block-uniform branch)
        float ss = 0.f;
#pragma unroll
        for (int i = 0; i < 2; ++i) ss += partials[i * 256 + tid];   // 512 partials
        float s = 0.f;
#pragma unroll
        for (int i = 0; i < 4; ++i) {
            float p = (float)hist[i * 256 + tid] * (1.0f / 65536.0f);
            s += p * logf(p + 1e-10f);
        }
#pragma unroll
        for (int off = 32; off; off >>= 1) {
            ss += __shfl_down(ss, off, 64);
            s  += __shfl_down(s, off, 64);
        }
        if ((tid & 63) == 0) { fin[tid >> 6] = ss; fin[4 + (tid >> 6)] = s; }
        __syncthreads();
        if (tid == 0) {
            float sse = fin[0] + fin[1] + fin[2] + fin[3] + *sse_corr;
            float ent = fin[4] + fin[5] + fin[6] + fin[7];
            out[OUT_ELEMS]     = 1.25f * sse * (1.0f / (float)OUT_ELEMS);  // loss
            out[OUT_ELEMS + 1] = expf(-ent);                                // perplexity
        }
    }
}

// ---------------------------------------------------------------- launch ----
extern "C" void kernel_launch(void* const* d_in, const int* in_sizes, int n_in,
                              void* d_out, int out_size, void* d_ws, size_t ws_size,
                              hipStream_t stream) {
    const float* x   = (const float*)d_in[0];
    const float* emb = (const float*)d_in[1];
    float* out = (float*)d_out;
    char* ws = (char*)d_ws;
    float*          enorm    = (float*)(ws);
    unsigned int*   hist     = (unsigned int*)(ws + 4096);
    unsigned int*   counter  = (unsigned int*)(ws + 8192);
    float*          sse_corr = (float*)(ws + 8196);
    short*          ehi      = (short*)(ws + 12288);
    short*          elo      = (short*)(ws + 143360);
    unsigned short* idx      = (unsigned short*)(ws + 274432);
    unsigned short* list     = (unsigned short*)(ws + 405504);
    float*          partials = (float*)(ws + 536576);

    k_prep  <<<64, 256, 0, stream>>>(emb, enorm, ehi, elo, hist, counter, sse_corr);
    k_argmin<<<N_TOTAL / QT, 256, 0, stream>>>(x, ehi, elo, enorm, idx, list, counter, hist, partials);
    k_rescue<<<RESCUE_BLOCKS, 256, 0, stream>>>(x, emb, enorm, list, counter, idx, hist, sse_corr);
    k_output<<<N_TOTAL / 64, 256, 0, stream>>>(x, emb, idx, out, partials, sse_corr, hist);
}